// Round 1
// baseline (514.389 us; speedup 1.0000x reference)
//
#include <hip/hip_runtime.h>
#include <hip/hip_bf16.h>
#include <cstdint>
#include <cstddef>

#define NEG_SLOPE 0.2f

// ---------------------------------------------------------------------------
// Tiled fp32 GEMM: C[M,N] = A[M,K] @ B[K,N], row-major. N % BN == 0, K % BK == 0.
// blockDim = (BM/TM)*(BN/TN) = 256.
// ---------------------------------------------------------------------------
template<int BM, int BN, int BK, int TM, int TN>
__global__ __launch_bounds__(256) void gemm_f32(
    const float* __restrict__ A, const float* __restrict__ B, float* __restrict__ C,
    int M, int N, int K)
{
    __shared__ float As[BK][BM + 4];
    __shared__ float Bs[BK][BN + 4];
    const int tid  = threadIdx.x;
    constexpr int NCG = BN / TN;
    const int tcol = tid % NCG;
    const int trow = tid / NCG;
    const int brow = blockIdx.y * BM;
    const int bcol = blockIdx.x * BN;

    float acc[TM][TN] = {};

    constexpr int A_IT = (BM * BK / 4) / 256;   // float4 loads per thread (A)
    constexpr int B_IT = (BK * BN / 4) / 256;   // float4 loads per thread (B)
    static_assert(A_IT >= 1 && B_IT >= 1, "tile too small");

    for (int k0 = 0; k0 < K; k0 += BK) {
        #pragma unroll
        for (int i = 0; i < A_IT; ++i) {
            int f  = tid + i * 256;
            int r  = f / (BK / 4);
            int kk = (f % (BK / 4)) * 4;
            int gr = brow + r;
            float4 v = make_float4(0.f, 0.f, 0.f, 0.f);
            if (gr < M) v = *(const float4*)&A[(size_t)gr * K + k0 + kk];
            As[kk + 0][r] = v.x; As[kk + 1][r] = v.y;
            As[kk + 2][r] = v.z; As[kk + 3][r] = v.w;
        }
        #pragma unroll
        for (int i = 0; i < B_IT; ++i) {
            int f  = tid + i * 256;
            int r  = f / (BN / 4);
            int cc = (f % (BN / 4)) * 4;
            float4 v = *(const float4*)&B[(size_t)(k0 + r) * N + bcol + cc];
            Bs[r][cc + 0] = v.x; Bs[r][cc + 1] = v.y;
            Bs[r][cc + 2] = v.z; Bs[r][cc + 3] = v.w;
        }
        __syncthreads();
        #pragma unroll
        for (int k = 0; k < BK; ++k) {
            float a[TM], b[TN];
            #pragma unroll
            for (int i = 0; i < TM; i += 4) {
                float4 v = *(const float4*)&As[k][trow * TM + i];
                a[i] = v.x; a[i + 1] = v.y; a[i + 2] = v.z; a[i + 3] = v.w;
            }
            #pragma unroll
            for (int j = 0; j < TN; j += 4) {
                float4 v = *(const float4*)&Bs[k][tcol * TN + j];
                b[j] = v.x; b[j + 1] = v.y; b[j + 2] = v.z; b[j + 3] = v.w;
            }
            #pragma unroll
            for (int i = 0; i < TM; ++i)
                #pragma unroll
                for (int j = 0; j < TN; ++j)
                    acc[i][j] = fmaf(a[i], b[j], acc[i][j]);
        }
        __syncthreads();
    }
    #pragma unroll
    for (int i = 0; i < TM; ++i) {
        int gr = brow + trow * TM + i;
        if (gr < M) {
            #pragma unroll
            for (int j = 0; j < TN; j += 4) {
                float4 v = make_float4(acc[i][j], acc[i][j + 1], acc[i][j + 2], acc[i][j + 3]);
                *(float4*)&C[(size_t)gr * N + bcol + tcol * TN + j] = v;
            }
        }
    }
}

// ---------------------------------------------------------------------------
// CSR build (edges with self-loops appended: e < E0 -> ei rows, else self loop)
// ---------------------------------------------------------------------------
__global__ void count_kernel(const int* __restrict__ ei, int* __restrict__ cnt,
                             int ET, int E0)
{
    int e = blockIdx.x * blockDim.x + threadIdx.x;
    if (e >= ET) return;
    int d = (e < E0) ? ei[E0 + e] : (e - E0);
    atomicAdd(&cnt[d], 1);
}

__global__ void scan_kernel(const int* __restrict__ cnt, int* __restrict__ offs, int n)
{
    __shared__ int tmp[256];
    __shared__ int carry_s;
    int t = threadIdx.x;
    if (t == 0) carry_s = 0;
    __syncthreads();
    for (int base = 0; base < n; base += 256) {
        int v = (base + t < n) ? cnt[base + t] : 0;
        tmp[t] = v;
        __syncthreads();
        for (int s = 1; s < 256; s <<= 1) {
            int add = (t >= s) ? tmp[t - s] : 0;
            __syncthreads();
            tmp[t] += add;
            __syncthreads();
        }
        int incl  = tmp[t];
        int carry = carry_s;
        if (base + t < n) offs[base + t] = carry + incl - v;
        __syncthreads();
        if (t == 255) carry_s = carry + incl;
        __syncthreads();
    }
    if (t == 0) offs[n] = carry_s;
}

__global__ void scatter_kernel(const int* __restrict__ ei, const int* __restrict__ offs,
                               int* __restrict__ cur, int* __restrict__ eid,
                               int ET, int E0)
{
    int e = blockIdx.x * blockDim.x + threadIdx.x;
    if (e >= ET) return;
    int d   = (e < E0) ? ei[E0 + e] : (e - E0);
    int pos = atomicAdd(&cur[d], 1);
    eid[offs[d] + pos] = e;
}

// ---------------------------------------------------------------------------
// alpha_s / alpha_d: one wave per (node, head). blockDim = 64*H, grid = N.
// ---------------------------------------------------------------------------
__global__ void attn_kernel(const float* __restrict__ h, const float* __restrict__ a_src,
                            const float* __restrict__ a_dst, float* __restrict__ as_,
                            float* __restrict__ ad_, int H, int C)
{
    int n     = blockIdx.x;
    int h_idx = threadIdx.x >> 6;
    int lane  = threadIdx.x & 63;
    const float* hp  = h + (size_t)n * H * C + (size_t)h_idx * C;
    const float* asp = a_src + (size_t)h_idx * C;
    const float* adp = a_dst + (size_t)h_idx * C;
    float vs = 0.f, vd = 0.f;
    for (int c = lane; c < C; c += 64) {
        float xv = hp[c];
        vs += xv * asp[c];
        vd += xv * adp[c];
    }
    #pragma unroll
    for (int s = 32; s > 0; s >>= 1) {
        vs += __shfl_down(vs, s);
        vd += __shfl_down(vd, s);
    }
    if (lane == 0) {
        as_[n * H + h_idx] = vs;
        ad_[n * H + h_idx] = vd;
    }
}

// ---------------------------------------------------------------------------
// Per-(dst, head) softmax stats (max + sum of exp) over incoming edges.
// ---------------------------------------------------------------------------
__global__ void smax_stats(const int* __restrict__ ei, const int* __restrict__ offs,
                           const int* __restrict__ eid, const float* __restrict__ as_,
                           const float* __restrict__ ad_, float* __restrict__ mout,
                           float* __restrict__ dout, int N, int H, int E0)
{
    int idx = blockIdx.x * blockDim.x + threadIdx.x;
    if (idx >= N * H) return;
    int n = idx / H, hh = idx % H;
    int s0 = offs[n], s1 = offs[n + 1];
    float adn = ad_[n * H + hh];
    float m = -1e30f;
    for (int j = s0; j < s1; ++j) {
        int e = eid[j];
        int s = (e < E0) ? ei[e] : (e - E0);
        float v = as_[s * H + hh] + adn;
        v = (v < 0.f) ? NEG_SLOPE * v : v;
        m = fmaxf(m, v);
    }
    float den = 0.f;
    for (int j = s0; j < s1; ++j) {
        int e = eid[j];
        int s = (e < E0) ? ei[e] : (e - E0);
        float v = as_[s * H + hh] + adn;
        v = (v < 0.f) ? NEG_SLOPE * v : v;
        den += __expf(v - m);
    }
    mout[idx] = m;
    dout[idx] = den;
}

// ---------------------------------------------------------------------------
// Edge softmax weights: w[e,h] = exp(lrelu(as[src]+ad[dst]) - m[dst]) / (den[dst]+eps)
// ---------------------------------------------------------------------------
__global__ void eweight(const int* __restrict__ ei, const float* __restrict__ as_,
                        const float* __restrict__ ad_, const float* __restrict__ m_,
                        const float* __restrict__ den_, float* __restrict__ w,
                        int ET, int H, int E0)
{
    int idx = blockIdx.x * blockDim.x + threadIdx.x;
    if (idx >= ET * H) return;
    int e = idx / H, hh = idx % H;
    int s = (e < E0) ? ei[e] : (e - E0);
    int d = (e < E0) ? ei[E0 + e] : (e - E0);
    float v = as_[s * H + hh] + ad_[d * H + hh];
    v = (v < 0.f) ? NEG_SLOPE * v : v;
    w[idx] = __expf(v - m_[d * H + hh]) / (den_[d * H + hh] + 1e-16f);
}

// ---------------------------------------------------------------------------
// Aggregation: out[n, col] = sum_{e: dst==n} w[e, col/C] * h[src_e, col] (+bias, relu)
// blockDim = min(HC, 256). Each thread covers col and col+blockDim.
// ---------------------------------------------------------------------------
__global__ void aggregate(const float* __restrict__ h, const float* __restrict__ w,
                          const int* __restrict__ offs, const int* __restrict__ eid,
                          const int* __restrict__ ei, const float* __restrict__ bias,
                          float* __restrict__ out, int E0, int H, int C, int HC,
                          int do_relu)
{
    int n   = blockIdx.x;
    int tid = threadIdx.x;
    int s0 = offs[n], s1 = offs[n + 1];
    int col0 = tid;
    int col1 = tid + blockDim.x;
    int hd0 = col0 / C;
    int hd1 = (col1 < HC) ? (col1 / C) : 0;
    float acc0 = 0.f, acc1 = 0.f;
    for (int j = s0; j < s1; ++j) {
        int e = eid[j];
        int s = (e < E0) ? ei[e] : (e - E0);
        const float* hrow = h + (size_t)s * HC;
        const float* wrow = w + (size_t)e * H;
        acc0 += wrow[hd0] * hrow[col0];
        if (col1 < HC) acc1 += wrow[hd1] * hrow[col1];
    }
    float r0 = acc0 + bias[col0];
    out[(size_t)n * HC + col0] = do_relu ? fmaxf(r0, 0.f) : r0;
    if (col1 < HC) {
        float r1 = acc1 + bias[col1];
        out[(size_t)n * HC + col1] = do_relu ? fmaxf(r1, 0.f) : r1;
    }
}

// ---------------------------------------------------------------------------
// Graph segment starts from sorted batch array.
// ---------------------------------------------------------------------------
__global__ void gstart_kernel(const int* __restrict__ batch, int* __restrict__ gstart,
                              int N, int G)
{
    int n = blockIdx.x * blockDim.x + threadIdx.x;
    if (n >= N) return;
    int b    = batch[n];
    int prev = (n == 0) ? -1 : batch[n - 1];
    for (int g = prev + 1; g <= b; ++g) gstart[g] = n;
    if (n == N - 1) {
        for (int g = b + 1; g <= G; ++g) gstart[g] = N;
    }
}

__global__ void pool_kernel(const float* __restrict__ out2, const int* __restrict__ gstart,
                            float* __restrict__ pooled, int C)
{
    int g = blockIdx.x;
    int c = threadIdx.x;
    int s = gstart[g], e = gstart[g + 1];
    float acc = 0.f;
    for (int n = s; n < e; ++n) acc += out2[(size_t)n * C + c];
    float cntf = (float)(e - s);
    pooled[(size_t)g * C + c] = acc / fmaxf(cntf, 1.0f);
}

// ---------------------------------------------------------------------------
// FC head: out[g] = fc2( relu( fc1(pooled[g]) ) )
// blockDim = 64 (one wave), grid = G.
// ---------------------------------------------------------------------------
__global__ void head_kernel(const float* __restrict__ pooled, const float* __restrict__ fc1W,
                            const float* __restrict__ fc1b, const float* __restrict__ fc2W,
                            const float* __restrict__ fc2b, float* __restrict__ out)
{
    int g = blockIdx.x;
    int j = threadIdx.x;           // 0..63
    float t = 0.f;
    for (int c = 0; c < 128; ++c)
        t += pooled[(size_t)g * 128 + c] * fc1W[c * 64 + j];
    t = fmaxf(t + fc1b[j], 0.f);
    float v = t * fc2W[j];
    #pragma unroll
    for (int s = 32; s > 0; s >>= 1) v += __shfl_down(v, s);
    if (j == 0) out[g] = v + fc2b[0];
}

// ---------------------------------------------------------------------------
extern "C" void kernel_launch(void* const* d_in, const int* in_sizes, int n_in,
                              void* d_out, int out_size, void* d_ws, size_t ws_size,
                              hipStream_t stream)
{
    const float* x    = (const float*)d_in[0];
    const int*   ei   = (const int*)d_in[1];
    const int*   batch= (const int*)d_in[2];
    const float* W1   = (const float*)d_in[3];
    const float* as1w = (const float*)d_in[4];
    const float* ad1w = (const float*)d_in[5];
    const float* b1   = (const float*)d_in[6];
    const float* W2   = (const float*)d_in[7];
    const float* as2w = (const float*)d_in[8];
    const float* ad2w = (const float*)d_in[9];
    const float* b2   = (const float*)d_in[10];
    const float* fc1W = (const float*)d_in[11];
    const float* fc1b = (const float*)d_in[12];
    const float* fc2W = (const float*)d_in[13];
    const float* fc2b = (const float*)d_in[14];
    float* out = (float*)d_out;

    const int D = 256, H1 = 4, C = 128, HC = H1 * C, G = 64;
    const int N  = in_sizes[0] / D;        // 20000
    const int E0 = in_sizes[1] / 2;        // 160000
    const int ET = E0 + N;                 // +self loops

    // workspace layout
    char* p = (char*)d_ws;
    auto alloc = [&](size_t bytes) -> char* {
        char* r = p;
        p += (bytes + 255) & ~(size_t)255;
        return r;
    };
    float* h1     = (float*)alloc((size_t)N * HC * 4);   // layer1 features; reused below
    float* out1   = (float*)alloc((size_t)N * HC * 4);   // layer1 output
    float* h2     = h1;                                  // layer2 features (h1 dead then)
    float* out2   = h1 + (size_t)N * C;                  // layer2 output (within h1 region)
    float* as_    = (float*)alloc((size_t)N * H1 * 4);
    float* ad_    = (float*)alloc((size_t)N * H1 * 4);
    float* m_     = (float*)alloc((size_t)N * H1 * 4);
    float* den_   = (float*)alloc((size_t)N * H1 * 4);
    float* wgt    = (float*)alloc((size_t)ET * H1 * 4);
    int*   cnt    = (int*)alloc((size_t)N * 4);
    int*   cur    = (int*)alloc((size_t)N * 4);
    int*   offs   = (int*)alloc((size_t)(N + 1) * 4);
    int*   eid    = (int*)alloc((size_t)ET * 4);
    int*   gstart = (int*)alloc((size_t)(G + 1) * 4);
    float* pooled = (float*)alloc((size_t)G * C * 4);

    // ---- CSR build (shared by both layers) ----
    hipMemsetAsync(cnt, 0, (size_t)N * 4, stream);
    hipMemsetAsync(cur, 0, (size_t)N * 4, stream);
    count_kernel<<<(ET + 255) / 256, 256, 0, stream>>>(ei, cnt, ET, E0);
    scan_kernel<<<1, 256, 0, stream>>>(cnt, offs, N);
    scatter_kernel<<<(ET + 255) / 256, 256, 0, stream>>>(ei, offs, cur, eid, ET, E0);

    // ---- Layer 1: GAT(256 -> 4 heads x 128, concat) + ReLU ----
    gemm_f32<128, 128, 16, 8, 8>
        <<<dim3(HC / 128, (N + 127) / 128), 256, 0, stream>>>(x, W1, h1, N, HC, D);
    attn_kernel<<<N, 64 * H1, 0, stream>>>(h1, as1w, ad1w, as_, ad_, H1, C);
    smax_stats<<<(N * H1 + 255) / 256, 256, 0, stream>>>(ei, offs, eid, as_, ad_, m_, den_, N, H1, E0);
    eweight<<<(ET * H1 + 255) / 256, 256, 0, stream>>>(ei, as_, ad_, m_, den_, wgt, ET, H1, E0);
    aggregate<<<N, 256, 0, stream>>>(h1, wgt, offs, eid, ei, b1, out1, E0, H1, C, HC, 1);

    // ---- Layer 2: GAT(512 -> 1 head x 128, mean over 1 head) ----
    gemm_f32<64, 64, 16, 4, 4>
        <<<dim3(C / 64, (N + 63) / 64), 256, 0, stream>>>(out1, W2, h2, N, C, HC);
    attn_kernel<<<N, 64, 0, stream>>>(h2, as2w, ad2w, as_, ad_, 1, C);
    smax_stats<<<(N + 255) / 256, 256, 0, stream>>>(ei, offs, eid, as_, ad_, m_, den_, N, 1, E0);
    eweight<<<(ET + 255) / 256, 256, 0, stream>>>(ei, as_, ad_, m_, den_, wgt, ET, 1, E0);
    aggregate<<<N, 128, 0, stream>>>(h2, wgt, offs, eid, ei, b2, out2, E0, 1, C, C, 0);

    // ---- Global mean pool + FC head ----
    gstart_kernel<<<(N + 255) / 256, 256, 0, stream>>>(batch, gstart, N, G);
    pool_kernel<<<G, C, 0, stream>>>(out2, gstart, pooled, C);
    head_kernel<<<G, 64, 0, stream>>>(pooled, fc1W, fc1b, fc2W, fc2b, out);
}

// Round 2
// 319.946 us; speedup vs baseline: 1.6077x; 1.6077x over previous
//
#include <hip/hip_runtime.h>
#include <hip/hip_bf16.h>
#include <cstdint>
#include <cstddef>

#define NEG_SLOPE 0.2f

// ---------------------------------------------------------------------------
// Tiled fp32 GEMM with fused GAT attention-score epilogue.
// C[M,N] = A[M,K] @ B[K,N] row-major. BN == 128 == head width, so each block's
// column range is exactly one attention head (head = blockIdx.x) and the
// epilogue can compute as_/ad_ = h . a_src/a_dst with a 16-lane shuffle reduce.
// Bs reads are split into two float4 groups (tcol*4 and 64+tcol*4) so the
// 64-lane wave hits banks at stride 4 (2-way, free) instead of stride 8 (4-way).
// ---------------------------------------------------------------------------
template<int BM, int BN, int BK, int TM, int TN>
__global__ __launch_bounds__(256) void gemm_attn(
    const float* __restrict__ A, const float* __restrict__ B, float* __restrict__ C,
    int M, int N, int K,
    const float* __restrict__ a_src, const float* __restrict__ a_dst,
    float* __restrict__ as_, float* __restrict__ ad_, int H)
{
    static_assert(BN == 128 && TN == 8, "layout assumes BN=128, TN=8");
    __shared__ float As[BK][BM + 4];
    __shared__ float Bs[BK][BN + 4];
    const int tid  = threadIdx.x;
    constexpr int NCG = BN / TN;          // 16
    const int tcol = tid % NCG;
    const int trow = tid / NCG;
    const int brow = blockIdx.y * BM;
    const int bcol = blockIdx.x * BN;
    const int head = blockIdx.x;

    float acc[TM][TN] = {};

    constexpr int A_IT = (BM * BK / 4) / 256;
    constexpr int B_IT = (BK * BN / 4) / 256;
    static_assert(A_IT >= 1 && B_IT >= 1, "tile too small");

    for (int k0 = 0; k0 < K; k0 += BK) {
        #pragma unroll
        for (int i = 0; i < A_IT; ++i) {
            int f  = tid + i * 256;
            int r  = f / (BK / 4);
            int kk = (f % (BK / 4)) * 4;
            int gr = brow + r;
            float4 v = make_float4(0.f, 0.f, 0.f, 0.f);
            if (gr < M) v = *(const float4*)&A[(size_t)gr * K + k0 + kk];
            As[kk + 0][r] = v.x; As[kk + 1][r] = v.y;
            As[kk + 2][r] = v.z; As[kk + 3][r] = v.w;
        }
        #pragma unroll
        for (int i = 0; i < B_IT; ++i) {
            int f  = tid + i * 256;
            int r  = f / (BN / 4);
            int cc = (f % (BN / 4)) * 4;
            float4 v = *(const float4*)&B[(size_t)(k0 + r) * N + bcol + cc];
            Bs[r][cc + 0] = v.x; Bs[r][cc + 1] = v.y;
            Bs[r][cc + 2] = v.z; Bs[r][cc + 3] = v.w;
        }
        __syncthreads();
        #pragma unroll
        for (int k = 0; k < BK; ++k) {
            float a[TM], b[TN];
            #pragma unroll
            for (int i = 0; i < TM; i += 4) {
                float4 v = *(const float4*)&As[k][trow * TM + i];
                a[i] = v.x; a[i + 1] = v.y; a[i + 2] = v.z; a[i + 3] = v.w;
            }
            {
                float4 v0 = *(const float4*)&Bs[k][tcol * 4];
                float4 v1 = *(const float4*)&Bs[k][NCG * 4 + tcol * 4];
                b[0] = v0.x; b[1] = v0.y; b[2] = v0.z; b[3] = v0.w;
                b[4] = v1.x; b[5] = v1.y; b[6] = v1.z; b[7] = v1.w;
            }
            #pragma unroll
            for (int i = 0; i < TM; ++i)
                #pragma unroll
                for (int j = 0; j < TN; ++j)
                    acc[i][j] = fmaf(a[i], b[j], acc[i][j]);
        }
        __syncthreads();
    }

    // C columns for this thread: c_lo = bcol + tcol*4 (+j), c_hi = bcol + 64 + tcol*4 (+j)
    #pragma unroll
    for (int i = 0; i < TM; ++i) {
        int gr = brow + trow * TM + i;
        if (gr < M) {
            float4 v0 = make_float4(acc[i][0], acc[i][1], acc[i][2], acc[i][3]);
            float4 v1 = make_float4(acc[i][4], acc[i][5], acc[i][6], acc[i][7]);
            *(float4*)&C[(size_t)gr * N + bcol + tcol * 4] = v0;
            *(float4*)&C[(size_t)gr * N + bcol + 64 + tcol * 4] = v1;
        }
    }

    // Fused attention-score epilogue: as_[n,head] = h[n, head*128 : head*128+128] . a_src[head]
    if (as_ != nullptr) {
        float4 s0 = *(const float4*)&a_src[head * BN + tcol * 4];
        float4 s1 = *(const float4*)&a_src[head * BN + 64 + tcol * 4];
        float4 d0 = *(const float4*)&a_dst[head * BN + tcol * 4];
        float4 d1 = *(const float4*)&a_dst[head * BN + 64 + tcol * 4];
        #pragma unroll
        for (int i = 0; i < TM; ++i) {
            float vs = acc[i][0] * s0.x + acc[i][1] * s0.y + acc[i][2] * s0.z + acc[i][3] * s0.w
                     + acc[i][4] * s1.x + acc[i][5] * s1.y + acc[i][6] * s1.z + acc[i][7] * s1.w;
            float vd = acc[i][0] * d0.x + acc[i][1] * d0.y + acc[i][2] * d0.z + acc[i][3] * d0.w
                     + acc[i][4] * d1.x + acc[i][5] * d1.y + acc[i][6] * d1.z + acc[i][7] * d1.w;
            #pragma unroll
            for (int m = 1; m < 16; m <<= 1) {
                vs += __shfl_xor(vs, m);
                vd += __shfl_xor(vd, m);
            }
            int gr = brow + trow * TM + i;
            if (tcol == 0 && gr < M) {
                as_[(size_t)gr * H + head] = vs;
                ad_[(size_t)gr * H + head] = vd;
            }
        }
    }
}

// ---------------------------------------------------------------------------
// CSR build (edges with self-loops appended: e < E0 -> ei rows, else self loop)
// ---------------------------------------------------------------------------
__global__ void count_kernel(const int* __restrict__ ei, int* __restrict__ cnt,
                             int ET, int E0)
{
    int e = blockIdx.x * blockDim.x + threadIdx.x;
    if (e >= ET) return;
    int d = (e < E0) ? ei[E0 + e] : (e - E0);
    atomicAdd(&cnt[d], 1);
}

// 3-phase exclusive scan of cnt[0..n) -> offs[0..n], offs[n] = total.
__global__ void scan1(const int* __restrict__ cnt, int* __restrict__ offs,
                      int* __restrict__ bsum, int n)
{
    __shared__ int tmp[256];
    int t = threadIdx.x;
    int i = blockIdx.x * 256 + t;
    int v = (i < n) ? cnt[i] : 0;
    tmp[t] = v;
    __syncthreads();
    for (int s = 1; s < 256; s <<= 1) {
        int a = (t >= s) ? tmp[t - s] : 0;
        __syncthreads();
        tmp[t] += a;
        __syncthreads();
    }
    if (i < n) offs[i] = tmp[t] - v;      // block-local exclusive
    if (t == 255) bsum[blockIdx.x] = tmp[255];
}

__global__ void scan2(const int* __restrict__ bsum, int* __restrict__ bofs,
                      int B, int* __restrict__ total_dst)
{
    __shared__ int tmp[256];
    int t = threadIdx.x;
    int v = (t < B) ? bsum[t] : 0;
    tmp[t] = v;
    __syncthreads();
    for (int s = 1; s < 256; s <<= 1) {
        int a = (t >= s) ? tmp[t - s] : 0;
        __syncthreads();
        tmp[t] += a;
        __syncthreads();
    }
    if (t < B) bofs[t] = tmp[t] - v;
    if (t == 255) *total_dst = tmp[255];
}

__global__ void scan3(int* __restrict__ offs, const int* __restrict__ bofs, int n)
{
    int i = blockIdx.x * 256 + threadIdx.x;
    if (i < n) offs[i] += bofs[blockIdx.x];
}

__global__ void scatter_kernel(const int* __restrict__ ei, const int* __restrict__ offs,
                               int* __restrict__ cur, int* __restrict__ eid,
                               int ET, int E0)
{
    int e = blockIdx.x * blockDim.x + threadIdx.x;
    if (e >= ET) return;
    int d   = (e < E0) ? ei[E0 + e] : (e - E0);
    int pos = atomicAdd(&cur[d], 1);
    eid[offs[d] + pos] = e;
}

// ---------------------------------------------------------------------------
// Per-(dst, head) softmax stats (max + sum of exp) over incoming edges.
// ---------------------------------------------------------------------------
__global__ void smax_stats(const int* __restrict__ ei, const int* __restrict__ offs,
                           const int* __restrict__ eid, const float* __restrict__ as_,
                           const float* __restrict__ ad_, float* __restrict__ mout,
                           float* __restrict__ dout, int N, int H, int E0)
{
    int idx = blockIdx.x * blockDim.x + threadIdx.x;
    if (idx >= N * H) return;
    int n = idx / H, hh = idx % H;
    int s0 = offs[n], s1 = offs[n + 1];
    float adn = ad_[n * H + hh];
    float m = -1e30f;
    for (int j = s0; j < s1; ++j) {
        int e = eid[j];
        int s = (e < E0) ? ei[e] : (e - E0);
        float v = as_[s * H + hh] + adn;
        v = (v < 0.f) ? NEG_SLOPE * v : v;
        m = fmaxf(m, v);
    }
    float den = 0.f;
    for (int j = s0; j < s1; ++j) {
        int e = eid[j];
        int s = (e < E0) ? ei[e] : (e - E0);
        float v = as_[s * H + hh] + adn;
        v = (v < 0.f) ? NEG_SLOPE * v : v;
        den += __expf(v - m);
    }
    mout[idx] = m;
    dout[idx] = den;
}

// ---------------------------------------------------------------------------
// Edge softmax weights.
// ---------------------------------------------------------------------------
__global__ void eweight(const int* __restrict__ ei, const float* __restrict__ as_,
                        const float* __restrict__ ad_, const float* __restrict__ m_,
                        const float* __restrict__ den_, float* __restrict__ w,
                        int ET, int H, int E0)
{
    int idx = blockIdx.x * blockDim.x + threadIdx.x;
    if (idx >= ET * H) return;
    int e = idx / H, hh = idx % H;
    int s = (e < E0) ? ei[e] : (e - E0);
    int d = (e < E0) ? ei[E0 + e] : (e - E0);
    float v = as_[s * H + hh] + ad_[d * H + hh];
    v = (v < 0.f) ? NEG_SLOPE * v : v;
    w[idx] = __expf(v - m_[d * H + hh]) / (den_[d * H + hh] + 1e-16f);
}

// ---------------------------------------------------------------------------
// Aggregation, float4 per thread: out[n, col..col+3] = sum_e w[e,hd]*h[src,col..col+3]
// ---------------------------------------------------------------------------
__global__ void aggregate(const float* __restrict__ h, const float* __restrict__ w,
                          const int* __restrict__ offs, const int* __restrict__ eid,
                          const int* __restrict__ ei, const float* __restrict__ bias,
                          float* __restrict__ out, int E0, int H, int C, int HC,
                          int do_relu)
{
    int n   = blockIdx.x;
    int tid = threadIdx.x;
    int col = tid * 4;
    if (col >= HC) return;
    int hd = col / C;
    int s0 = offs[n], s1 = offs[n + 1];
    float4 acc = make_float4(0.f, 0.f, 0.f, 0.f);
    for (int j = s0; j < s1; ++j) {
        int e = eid[j];
        int s = (e < E0) ? ei[e] : (e - E0);
        float wv = w[(size_t)e * H + hd];
        float4 hv = *(const float4*)&h[(size_t)s * HC + col];
        acc.x = fmaf(wv, hv.x, acc.x);
        acc.y = fmaf(wv, hv.y, acc.y);
        acc.z = fmaf(wv, hv.z, acc.z);
        acc.w = fmaf(wv, hv.w, acc.w);
    }
    float4 bv = *(const float4*)&bias[col];
    acc.x += bv.x; acc.y += bv.y; acc.z += bv.z; acc.w += bv.w;
    if (do_relu) {
        acc.x = fmaxf(acc.x, 0.f); acc.y = fmaxf(acc.y, 0.f);
        acc.z = fmaxf(acc.z, 0.f); acc.w = fmaxf(acc.w, 0.f);
    }
    *(float4*)&out[(size_t)n * HC + col] = acc;
}

// ---------------------------------------------------------------------------
// Graph segment starts + 2-stage mean pool.
// ---------------------------------------------------------------------------
__global__ void gstart_kernel(const int* __restrict__ batch, int* __restrict__ gstart,
                              int N, int G)
{
    int n = blockIdx.x * blockDim.x + threadIdx.x;
    if (n >= N) return;
    int b    = batch[n];
    int prev = (n == 0) ? -1 : batch[n - 1];
    for (int g = prev + 1; g <= b; ++g) gstart[g] = n;
    if (n == N - 1) {
        for (int g = b + 1; g <= G; ++g) gstart[g] = N;
    }
}

#define POOL_S 16
__global__ void pool_stage1(const float* __restrict__ out2, const int* __restrict__ gstart,
                            float* __restrict__ partial, int C)
{
    int g = blockIdx.x, slice = blockIdx.y;
    int c = threadIdx.x;
    int s = gstart[g], e = gstart[g + 1];
    int len = e - s;
    int chunk = (len + POOL_S - 1) / POOL_S;
    int n0 = s + slice * chunk;
    int n1 = min(n0 + chunk, e);
    float acc = 0.f;
    for (int n = n0; n < n1; ++n) acc += out2[(size_t)n * C + c];
    partial[((size_t)g * POOL_S + slice) * C + c] = acc;
}

__global__ void pool_stage2(const float* __restrict__ partial, const int* __restrict__ gstart,
                            float* __restrict__ pooled, int C)
{
    int g = blockIdx.x;
    int c = threadIdx.x;
    float acc = 0.f;
    #pragma unroll
    for (int s = 0; s < POOL_S; ++s)
        acc += partial[((size_t)g * POOL_S + s) * C + c];
    float cntf = (float)(gstart[g + 1] - gstart[g]);
    pooled[(size_t)g * C + c] = acc / fmaxf(cntf, 1.0f);
}

// ---------------------------------------------------------------------------
// FC head.
// ---------------------------------------------------------------------------
__global__ void head_kernel(const float* __restrict__ pooled, const float* __restrict__ fc1W,
                            const float* __restrict__ fc1b, const float* __restrict__ fc2W,
                            const float* __restrict__ fc2b, float* __restrict__ out)
{
    int g = blockIdx.x;
    int j = threadIdx.x;           // 0..63
    float t = 0.f;
    for (int c = 0; c < 128; ++c)
        t += pooled[(size_t)g * 128 + c] * fc1W[c * 64 + j];
    t = fmaxf(t + fc1b[j], 0.f);
    float v = t * fc2W[j];
    #pragma unroll
    for (int s = 32; s > 0; s >>= 1) v += __shfl_down(v, s);
    if (j == 0) out[g] = v + fc2b[0];
}

// ---------------------------------------------------------------------------
extern "C" void kernel_launch(void* const* d_in, const int* in_sizes, int n_in,
                              void* d_out, int out_size, void* d_ws, size_t ws_size,
                              hipStream_t stream)
{
    const float* x    = (const float*)d_in[0];
    const int*   ei   = (const int*)d_in[1];
    const int*   batch= (const int*)d_in[2];
    const float* W1   = (const float*)d_in[3];
    const float* as1w = (const float*)d_in[4];
    const float* ad1w = (const float*)d_in[5];
    const float* b1   = (const float*)d_in[6];
    const float* W2   = (const float*)d_in[7];
    const float* as2w = (const float*)d_in[8];
    const float* ad2w = (const float*)d_in[9];
    const float* b2   = (const float*)d_in[10];
    const float* fc1W = (const float*)d_in[11];
    const float* fc1b = (const float*)d_in[12];
    const float* fc2W = (const float*)d_in[13];
    const float* fc2b = (const float*)d_in[14];
    float* out = (float*)d_out;

    const int D = 256, H1 = 4, C = 128, HC = H1 * C, G = 64;
    const int N  = in_sizes[0] / D;        // 20000
    const int E0 = in_sizes[1] / 2;        // 160000
    const int ET = E0 + N;
    const int NB = (N + 255) / 256;        // scan blocks (79)

    char* p = (char*)d_ws;
    auto alloc = [&](size_t bytes) -> char* {
        char* r = p;
        p += (bytes + 255) & ~(size_t)255;
        return r;
    };
    float* h1     = (float*)alloc((size_t)N * HC * 4);   // layer1 features; reused below
    float* out1   = (float*)alloc((size_t)N * HC * 4);
    float* h2     = h1;                                  // layer2 features (h1 dead then)
    float* out2   = h1 + (size_t)N * C;                  // disjoint from h2 reads
    float* as_    = (float*)alloc((size_t)N * H1 * 4);
    float* ad_    = (float*)alloc((size_t)N * H1 * 4);
    float* m_     = (float*)alloc((size_t)N * H1 * 4);
    float* den_   = (float*)alloc((size_t)N * H1 * 4);
    float* wgt    = (float*)alloc((size_t)ET * H1 * 4);
    int*   cnt    = (int*)alloc((size_t)N * 4);
    int*   cur    = (int*)alloc((size_t)N * 4);
    int*   offs   = (int*)alloc((size_t)(N + 1) * 4);
    int*   eid    = (int*)alloc((size_t)ET * 4);
    int*   bsum   = (int*)alloc(256 * 4);
    int*   bofs   = (int*)alloc(256 * 4);
    int*   gstart = (int*)alloc((size_t)(G + 1) * 4);
    float* partial= (float*)alloc((size_t)G * POOL_S * C * 4);
    float* pooled = (float*)alloc((size_t)G * C * 4);

    // ---- CSR build (shared by both layers) ----
    hipMemsetAsync(cnt, 0, (size_t)N * 4, stream);
    hipMemsetAsync(cur, 0, (size_t)N * 4, stream);
    count_kernel<<<(ET + 255) / 256, 256, 0, stream>>>(ei, cnt, ET, E0);
    scan1<<<NB, 256, 0, stream>>>(cnt, offs, bsum, N);
    scan2<<<1, 256, 0, stream>>>(bsum, bofs, NB, offs + N);
    scan3<<<NB, 256, 0, stream>>>(offs, bofs, N);
    scatter_kernel<<<(ET + 255) / 256, 256, 0, stream>>>(ei, offs, cur, eid, ET, E0);

    // ---- Layer 1: GAT(256 -> 4 heads x 128, concat) + ReLU ----
    gemm_attn<128, 128, 16, 8, 8>
        <<<dim3(HC / 128, (N + 127) / 128), 256, 0, stream>>>(
            x, W1, h1, N, HC, D, as1w, ad1w, as_, ad_, H1);
    smax_stats<<<(N * H1 + 255) / 256, 256, 0, stream>>>(ei, offs, eid, as_, ad_, m_, den_, N, H1, E0);
    eweight<<<(ET * H1 + 255) / 256, 256, 0, stream>>>(ei, as_, ad_, m_, den_, wgt, ET, H1, E0);
    aggregate<<<N, 128, 0, stream>>>(h1, wgt, offs, eid, ei, b1, out1, E0, H1, C, HC, 1);

    // ---- Layer 2: GAT(512 -> 1 head x 128, mean over single head) ----
    gemm_attn<64, 128, 16, 4, 8>
        <<<dim3(C / 128, (N + 63) / 64), 256, 0, stream>>>(
            out1, W2, h2, N, C, HC, as2w, ad2w, as_, ad_, 1);
    smax_stats<<<(N + 255) / 256, 256, 0, stream>>>(ei, offs, eid, as_, ad_, m_, den_, N, 1, E0);
    eweight<<<(ET + 255) / 256, 256, 0, stream>>>(ei, as_, ad_, m_, den_, wgt, ET, 1, E0);
    aggregate<<<N, 64, 0, stream>>>(h2, wgt, offs, eid, ei, b2, out2, E0, 1, C, C, 0);

    // ---- Global mean pool + FC head ----
    gstart_kernel<<<(N + 255) / 256, 256, 0, stream>>>(batch, gstart, N, G);
    pool_stage1<<<dim3(G, POOL_S), C, 0, stream>>>(out2, gstart, partial, C);
    pool_stage2<<<G, C, 0, stream>>>(partial, gstart, pooled, C);
    head_kernel<<<G, 64, 0, stream>>>(pooled, fc1W, fc1b, fc2W, fc2b, out);
}

// Round 3
// 229.007 us; speedup vs baseline: 2.2462x; 1.3971x over previous
//
#include <hip/hip_runtime.h>
#include <hip/hip_bf16.h>
#include <cstdint>
#include <cstddef>

#define NEG_SLOPE 0.2f

typedef __attribute__((ext_vector_type(8))) __bf16 bf16x8;
typedef __attribute__((ext_vector_type(4))) __bf16 bf16x4;
typedef __attribute__((ext_vector_type(4))) float  f32x4;

// ---------------------------------------------------------------------------
// No-LDS MFMA GEMM: C[M,N] = A[M,K] @ (Bhi + Blo)[K,N], A bf16 row-major,
// B stored TRANSPOSED [N][K] bf16 (hi/lo split of fp32 weights).
// Block = 256 thr = 4 waves (2x2); wave tile = (16*MF) x (16*NF).
// Fragments loaded straight from global (16B/lane, L1/L2-resident panels).
// mfma_f32_16x16x32_bf16: A-frag lane l -> row l&15, k=(l>>4)*8..+8 (16B
// contiguous); B-frag same with B^T rows; C/D: col=lane&15, row=(l>>4)*4+j.
// ---------------------------------------------------------------------------
template<int MF, int NF, bool STORE_BF16>
__global__ __launch_bounds__(256) void gemm_mfma(
    const __bf16* __restrict__ A, const __bf16* __restrict__ Bhi,
    const __bf16* __restrict__ Blo, void* __restrict__ Cout,
    int M, int N, int K)
{
    const int tid  = threadIdx.x;
    const int wave = tid >> 6, lane = tid & 63;
    const int wr = wave >> 1, wc = wave & 1;
    const int rowbase = blockIdx.y * (32 * MF) + wr * (16 * MF);
    const int colbase = blockIdx.x * (32 * NF) + wc * (16 * NF);
    const int l15 = lane & 15, kg = lane >> 4;

    size_t aoff[MF], boff[NF];
    #pragma unroll
    for (int mf = 0; mf < MF; ++mf) {
        int r = rowbase + mf * 16 + l15;
        if (r > M - 1) r = M - 1;              // clamp tail rows (stores guarded)
        aoff[mf] = (size_t)r * K + kg * 8;
    }
    #pragma unroll
    for (int nf = 0; nf < NF; ++nf) {
        int c = colbase + nf * 16 + l15;
        boff[nf] = (size_t)c * K + kg * 8;
    }

    f32x4 acc[MF][NF];
    #pragma unroll
    for (int mf = 0; mf < MF; ++mf)
        #pragma unroll
        for (int nf = 0; nf < NF; ++nf)
            acc[mf][nf] = (f32x4){0.f, 0.f, 0.f, 0.f};

    #pragma unroll 2
    for (int k0 = 0; k0 < K; k0 += 32) {
        bf16x8 af[MF], bh[NF], bl[NF];
        #pragma unroll
        for (int mf = 0; mf < MF; ++mf)
            af[mf] = *(const bf16x8*)(A + aoff[mf] + k0);
        #pragma unroll
        for (int nf = 0; nf < NF; ++nf) {
            bh[nf] = *(const bf16x8*)(Bhi + boff[nf] + k0);
            bl[nf] = *(const bf16x8*)(Blo + boff[nf] + k0);
        }
        #pragma unroll
        for (int mf = 0; mf < MF; ++mf)
            #pragma unroll
            for (int nf = 0; nf < NF; ++nf) {
                acc[mf][nf] = __builtin_amdgcn_mfma_f32_16x16x32_bf16(af[mf], bh[nf], acc[mf][nf], 0, 0, 0);
                acc[mf][nf] = __builtin_amdgcn_mfma_f32_16x16x32_bf16(af[mf], bl[nf], acc[mf][nf], 0, 0, 0);
            }
    }

    #pragma unroll
    for (int mf = 0; mf < MF; ++mf)
        #pragma unroll
        for (int j = 0; j < 4; ++j) {
            int r = rowbase + mf * 16 + kg * 4 + j;
            if (r < M) {
                #pragma unroll
                for (int nf = 0; nf < NF; ++nf) {
                    int c = colbase + nf * 16 + l15;
                    if (STORE_BF16)
                        ((__bf16*)Cout)[(size_t)r * N + c] = (__bf16)acc[mf][nf][j];
                    else
                        ((float*)Cout)[(size_t)r * N + c] = acc[mf][nf][j];
                }
            }
        }
}

// ---------------------------------------------------------------------------
// Weight prep: transpose + hi/lo bf16 split of W1 (256x512) and W2 (512x128).
// ---------------------------------------------------------------------------
__global__ void cvtw_kernel(const float* __restrict__ W1, const float* __restrict__ W2,
                            __bf16* __restrict__ w1thi, __bf16* __restrict__ w1tlo,
                            __bf16* __restrict__ w2thi, __bf16* __restrict__ w2tlo)
{
    int i = blockIdx.x * 256 + threadIdx.x;
    if (i < 256 * 512) {
        int k = i >> 9, n = i & 511;
        float w = W1[i];
        __bf16 hi = (__bf16)w;
        __bf16 lo = (__bf16)(w - (float)hi);
        w1thi[n * 256 + k] = hi;
        w1tlo[n * 256 + k] = lo;
    } else {
        int j = i - 256 * 512;
        if (j < 512 * 128) {
            int k = j >> 7, n = j & 127;
            float w = W2[j];
            __bf16 hi = (__bf16)w;
            __bf16 lo = (__bf16)(w - (float)hi);
            w2thi[n * 512 + k] = hi;
            w2tlo[n * 512 + k] = lo;
        }
    }
}

// ---------------------------------------------------------------------------
// Attention vectors folded through W:  wsd1[v][k] = sum_c W1[k, h*128+c]*a1[h,c]
// (v = 2h + {0:src,1:dst}), wsd2[v][k] = sum_c W2[k,c]*a2[c].
// ---------------------------------------------------------------------------
__global__ void attvec_kernel(const float* __restrict__ W1, const float* __restrict__ as1w,
                              const float* __restrict__ ad1w, const float* __restrict__ W2,
                              const float* __restrict__ as2w, const float* __restrict__ ad2w,
                              float* __restrict__ wsd1, float* __restrict__ wsd2)
{
    int t = blockIdx.x * 256 + threadIdx.x;
    if (t < 2048) {
        int k = t >> 3, v = t & 7, h = v >> 1;
        const float* av = (v & 1) ? (ad1w + h * 128) : (as1w + h * 128);
        float s = 0.f;
        for (int c = 0; c < 128; ++c) s += W1[k * 512 + h * 128 + c] * av[c];
        wsd1[v * 256 + k] = s;
    } else if (t < 3072) {
        int t2 = t - 2048;
        int k = t2 >> 1, v = t2 & 1;
        const float* av = v ? ad2w : as2w;
        float s = 0.f;
        for (int c = 0; c < 128; ++c) s += W2[k * 128 + c] * av[c];
        wsd2[v * 512 + k] = s;
    }
}

// ---------------------------------------------------------------------------
// x -> bf16 + fused layer-1 attention scores (as1/ad1 = x . wsd1[v]).
// One wave per row (K=256 = 64 lanes x float4). Grid = N/4, block 256.
// ---------------------------------------------------------------------------
__global__ __launch_bounds__(256) void cvtx_kernel(
    const float* __restrict__ x, const float* __restrict__ wsd1,
    __bf16* __restrict__ xb, float* __restrict__ as1_, float* __restrict__ ad1_, int N)
{
    int wave = threadIdx.x >> 6, lane = threadIdx.x & 63;
    int n = blockIdx.x * 4 + wave;
    if (n >= N) return;
    float4 xv = *(const float4*)&x[(size_t)n * 256 + lane * 4];
    bf16x4 xo;
    xo[0] = (__bf16)xv.x; xo[1] = (__bf16)xv.y; xo[2] = (__bf16)xv.z; xo[3] = (__bf16)xv.w;
    *(bf16x4*)&xb[(size_t)n * 256 + lane * 4] = xo;
    float p[8];
    #pragma unroll
    for (int v = 0; v < 8; ++v) {
        float4 wv = *(const float4*)&wsd1[v * 256 + lane * 4];
        p[v] = xv.x * wv.x + xv.y * wv.y + xv.z * wv.z + xv.w * wv.w;
    }
    #pragma unroll
    for (int v = 0; v < 8; ++v)
        #pragma unroll
        for (int s = 1; s < 64; s <<= 1) p[v] += __shfl_xor(p[v], s);
    if (lane == 0) {
        #pragma unroll
        for (int h = 0; h < 4; ++h) {
            as1_[n * 4 + h] = p[2 * h];
            ad1_[n * 4 + h] = p[2 * h + 1];
        }
    }
}

// ---------------------------------------------------------------------------
// CSR build.
// ---------------------------------------------------------------------------
__global__ void count_kernel(const int* __restrict__ ei, int* __restrict__ cnt,
                             int ET, int E0)
{
    int e = blockIdx.x * blockDim.x + threadIdx.x;
    if (e >= ET) return;
    int d = (e < E0) ? ei[E0 + e] : (e - E0);
    atomicAdd(&cnt[d], 1);
}

__global__ void scan1(const int* __restrict__ cnt, int* __restrict__ offs,
                      int* __restrict__ bsum, int n)
{
    __shared__ int tmp[256];
    int t = threadIdx.x;
    int i = blockIdx.x * 256 + t;
    int v = (i < n) ? cnt[i] : 0;
    tmp[t] = v;
    __syncthreads();
    for (int s = 1; s < 256; s <<= 1) {
        int a = (t >= s) ? tmp[t - s] : 0;
        __syncthreads();
        tmp[t] += a;
        __syncthreads();
    }
    if (i < n) offs[i] = tmp[t] - v;
    if (t == 255) bsum[blockIdx.x] = tmp[255];
}

__global__ void scan2(const int* __restrict__ bsum, int* __restrict__ bofs,
                      int B, int* __restrict__ total_dst)
{
    __shared__ int tmp[256];
    int t = threadIdx.x;
    int v = (t < B) ? bsum[t] : 0;
    tmp[t] = v;
    __syncthreads();
    for (int s = 1; s < 256; s <<= 1) {
        int a = (t >= s) ? tmp[t - s] : 0;
        __syncthreads();
        tmp[t] += a;
        __syncthreads();
    }
    if (t < B) bofs[t] = tmp[t] - v;
    if (t == 255) *total_dst = tmp[255];
}

__global__ void scan3(int* __restrict__ offs, const int* __restrict__ bofs, int n)
{
    int i = blockIdx.x * 256 + threadIdx.x;
    if (i < n) offs[i] += bofs[blockIdx.x];
}

__global__ void scatter_kernel(const int* __restrict__ ei, const int* __restrict__ offs,
                               int* __restrict__ cur, int* __restrict__ eid,
                               int ET, int E0)
{
    int e = blockIdx.x * blockDim.x + threadIdx.x;
    if (e >= ET) return;
    int d   = (e < E0) ? ei[E0 + e] : (e - E0);
    int pos = atomicAdd(&cur[d], 1);
    eid[offs[d] + pos] = e;
}

// ---------------------------------------------------------------------------
// Layer-1 aggregate: fused segment-softmax stats + edge weights + weighted sum
// + bias + relu + bf16 store + fused layer-2 attention scores (dot with wsd2).
// Block = 128 thr per dst node; thread t owns cols t*4..t*4+3, head = t>>5.
// ---------------------------------------------------------------------------
__global__ __launch_bounds__(128) void aggregate1_kernel(
    const __bf16* __restrict__ h1b, const int* __restrict__ offs,
    const int* __restrict__ eid, const int* __restrict__ ei,
    const float* __restrict__ as1_, const float* __restrict__ ad1_,
    const float* __restrict__ b1, const float* __restrict__ wsd2,
    __bf16* __restrict__ out1b, float* __restrict__ as2_, float* __restrict__ ad2_,
    int E0)
{
    int n = blockIdx.x;
    int t = threadIdx.x;
    int lane = t & 63, wave = t >> 6;
    int hd = t >> 5;
    int l32 = t & 31;
    int s0 = offs[n], s1 = offs[n + 1];
    float adn = ad1_[n * 4 + hd];
    __shared__ float sm_m[4], sm_inv[4];

    float m = -1e30f;
    for (int j = s0 + l32; j < s1; j += 32) {
        int e = eid[j];
        int s = (e < E0) ? ei[e] : (e - E0);
        float v = as1_[s * 4 + hd] + adn;
        v = (v < 0.f) ? NEG_SLOPE * v : v;
        m = fmaxf(m, v);
    }
    #pragma unroll
    for (int s_ = 1; s_ < 32; s_ <<= 1) m = fmaxf(m, __shfl_xor(m, s_));
    float den = 0.f;
    for (int j = s0 + l32; j < s1; j += 32) {
        int e = eid[j];
        int s = (e < E0) ? ei[e] : (e - E0);
        float v = as1_[s * 4 + hd] + adn;
        v = (v < 0.f) ? NEG_SLOPE * v : v;
        den += __expf(v - m);
    }
    #pragma unroll
    for (int s_ = 1; s_ < 32; s_ <<= 1) den += __shfl_xor(den, s_);
    if (l32 == 0) { sm_m[hd] = m; sm_inv[hd] = 1.f / (den + 1e-16f); }
    __syncthreads();
    m = sm_m[hd];
    float inv = sm_inv[hd];

    float a0 = 0.f, a1 = 0.f, a2 = 0.f, a3 = 0.f;
    for (int j = s0; j < s1; ++j) {
        int e = eid[j];
        int s = (e < E0) ? ei[e] : (e - E0);
        float v = as1_[s * 4 + hd] + adn;           // same addr across 32 lanes: broadcast
        v = (v < 0.f) ? NEG_SLOPE * v : v;
        float w = __expf(v - m) * inv;
        bf16x4 hv = *(const bf16x4*)&h1b[(size_t)s * 512 + t * 4];
        a0 = fmaf(w, (float)hv[0], a0);
        a1 = fmaf(w, (float)hv[1], a1);
        a2 = fmaf(w, (float)hv[2], a2);
        a3 = fmaf(w, (float)hv[3], a3);
    }
    float o0 = fmaxf(a0 + b1[t * 4 + 0], 0.f);
    float o1 = fmaxf(a1 + b1[t * 4 + 1], 0.f);
    float o2 = fmaxf(a2 + b1[t * 4 + 2], 0.f);
    float o3 = fmaxf(a3 + b1[t * 4 + 3], 0.f);
    bf16x4 ov;
    ov[0] = (__bf16)o0; ov[1] = (__bf16)o1; ov[2] = (__bf16)o2; ov[3] = (__bf16)o3;
    *(bf16x4*)&out1b[(size_t)n * 512 + t * 4] = ov;

    float ps = o0 * wsd2[t * 4 + 0] + o1 * wsd2[t * 4 + 1]
             + o2 * wsd2[t * 4 + 2] + o3 * wsd2[t * 4 + 3];
    float pd = o0 * wsd2[512 + t * 4 + 0] + o1 * wsd2[512 + t * 4 + 1]
             + o2 * wsd2[512 + t * 4 + 2] + o3 * wsd2[512 + t * 4 + 3];
    #pragma unroll
    for (int s_ = 1; s_ < 64; s_ <<= 1) {
        ps += __shfl_xor(ps, s_);
        pd += __shfl_xor(pd, s_);
    }
    __shared__ float red[4];
    if (lane == 0) { red[wave * 2] = ps; red[wave * 2 + 1] = pd; }
    __syncthreads();
    if (t == 0) {
        as2_[n] = red[0] + red[2];
        ad2_[n] = red[1] + red[3];
    }
}

// ---------------------------------------------------------------------------
// Layer-2 aggregate (H=1): one wave per dst node; thread owns cols lane*2..+1.
// ---------------------------------------------------------------------------
__global__ __launch_bounds__(64) void aggregate2_kernel(
    const float* __restrict__ h2, const int* __restrict__ offs,
    const int* __restrict__ eid, const int* __restrict__ ei,
    const float* __restrict__ as2_, const float* __restrict__ ad2_,
    const float* __restrict__ b2, float* __restrict__ out2, int E0)
{
    int n = blockIdx.x, lane = threadIdx.x;
    int s0 = offs[n], s1 = offs[n + 1];
    float adn = ad2_[n];
    float m = -1e30f;
    for (int j = s0 + lane; j < s1; j += 64) {
        int e = eid[j];
        int s = (e < E0) ? ei[e] : (e - E0);
        float v = as2_[s] + adn;
        v = (v < 0.f) ? NEG_SLOPE * v : v;
        m = fmaxf(m, v);
    }
    #pragma unroll
    for (int s_ = 1; s_ < 64; s_ <<= 1) m = fmaxf(m, __shfl_xor(m, s_));
    float den = 0.f;
    for (int j = s0 + lane; j < s1; j += 64) {
        int e = eid[j];
        int s = (e < E0) ? ei[e] : (e - E0);
        float v = as2_[s] + adn;
        v = (v < 0.f) ? NEG_SLOPE * v : v;
        den += __expf(v - m);
    }
    #pragma unroll
    for (int s_ = 1; s_ < 64; s_ <<= 1) den += __shfl_xor(den, s_);
    float inv = 1.f / (den + 1e-16f);

    float a0 = 0.f, a1 = 0.f;
    for (int j = s0; j < s1; ++j) {
        int e = eid[j];
        int s = (e < E0) ? ei[e] : (e - E0);
        float v = as2_[s] + adn;
        v = (v < 0.f) ? NEG_SLOPE * v : v;
        float w = __expf(v - m) * inv;
        float2 hv = *(const float2*)&h2[(size_t)s * 128 + lane * 2];
        a0 = fmaf(w, hv.x, a0);
        a1 = fmaf(w, hv.y, a1);
    }
    float2 o;
    o.x = a0 + b2[lane * 2 + 0];
    o.y = a1 + b2[lane * 2 + 1];
    *(float2*)&out2[(size_t)n * 128 + lane * 2] = o;
}

// ---------------------------------------------------------------------------
// Graph segment starts + 2-stage mean pool + FC head.
// ---------------------------------------------------------------------------
__global__ void gstart_kernel(const int* __restrict__ batch, int* __restrict__ gstart,
                              int N, int G)
{
    int n = blockIdx.x * blockDim.x + threadIdx.x;
    if (n >= N) return;
    int b    = batch[n];
    int prev = (n == 0) ? -1 : batch[n - 1];
    for (int g = prev + 1; g <= b; ++g) gstart[g] = n;
    if (n == N - 1) {
        for (int g = b + 1; g <= G; ++g) gstart[g] = N;
    }
}

#define POOL_S 16
__global__ void pool_stage1(const float* __restrict__ out2, const int* __restrict__ gstart,
                            float* __restrict__ partial, int C)
{
    int g = blockIdx.x, slice = blockIdx.y;
    int c = threadIdx.x;
    int s = gstart[g], e = gstart[g + 1];
    int len = e - s;
    int chunk = (len + POOL_S - 1) / POOL_S;
    int n0 = s + slice * chunk;
    int n1 = min(n0 + chunk, e);
    float acc = 0.f;
    for (int n = n0; n < n1; ++n) acc += out2[(size_t)n * C + c];
    partial[((size_t)g * POOL_S + slice) * C + c] = acc;
}

__global__ void pool_stage2(const float* __restrict__ partial, const int* __restrict__ gstart,
                            float* __restrict__ pooled, int C)
{
    int g = blockIdx.x;
    int c = threadIdx.x;
    float acc = 0.f;
    #pragma unroll
    for (int s = 0; s < POOL_S; ++s)
        acc += partial[((size_t)g * POOL_S + s) * C + c];
    float cntf = (float)(gstart[g + 1] - gstart[g]);
    pooled[(size_t)g * C + c] = acc / fmaxf(cntf, 1.0f);
}

__global__ void head_kernel(const float* __restrict__ pooled, const float* __restrict__ fc1W,
                            const float* __restrict__ fc1b, const float* __restrict__ fc2W,
                            const float* __restrict__ fc2b, float* __restrict__ out)
{
    int g = blockIdx.x;
    int j = threadIdx.x;           // 0..63
    float t = 0.f;
    for (int c = 0; c < 128; ++c)
        t += pooled[(size_t)g * 128 + c] * fc1W[c * 64 + j];
    t = fmaxf(t + fc1b[j], 0.f);
    float v = t * fc2W[j];
    #pragma unroll
    for (int s = 32; s > 0; s >>= 1) v += __shfl_down(v, s);
    if (j == 0) out[g] = v + fc2b[0];
}

// ---------------------------------------------------------------------------
extern "C" void kernel_launch(void* const* d_in, const int* in_sizes, int n_in,
                              void* d_out, int out_size, void* d_ws, size_t ws_size,
                              hipStream_t stream)
{
    const float* x    = (const float*)d_in[0];
    const int*   ei   = (const int*)d_in[1];
    const int*   batch= (const int*)d_in[2];
    const float* W1   = (const float*)d_in[3];
    const float* as1w = (const float*)d_in[4];
    const float* ad1w = (const float*)d_in[5];
    const float* b1   = (const float*)d_in[6];
    const float* W2   = (const float*)d_in[7];
    const float* as2w = (const float*)d_in[8];
    const float* ad2w = (const float*)d_in[9];
    const float* b2   = (const float*)d_in[10];
    const float* fc1W = (const float*)d_in[11];
    const float* fc1b = (const float*)d_in[12];
    const float* fc2W = (const float*)d_in[13];
    const float* fc2b = (const float*)d_in[14];
    float* out = (float*)d_out;

    const int D = 256, H1 = 4, C = 128, HC = 512, G = 64;
    const int N  = in_sizes[0] / D;        // 20000
    const int E0 = in_sizes[1] / 2;        // 160000
    const int ET = E0 + N;
    const int NB = (N + 255) / 256;

    char* p = (char*)d_ws;
    auto alloc = [&](size_t bytes) -> char* {
        char* r = p;
        p += (bytes + 255) & ~(size_t)255;
        return r;
    };
    __bf16* xb    = (__bf16*)alloc((size_t)N * D * 2);    // reused as h2 (f32 N*128, same bytes)
    float*  h2    = (float*)xb;
    __bf16* h1b   = (__bf16*)alloc((size_t)N * HC * 2);   // reused as out2 (f32 N*128)
    float*  out2  = (float*)h1b;
    __bf16* out1b = (__bf16*)alloc((size_t)N * HC * 2);
    __bf16* w1thi = (__bf16*)alloc((size_t)256 * 512 * 2);
    __bf16* w1tlo = (__bf16*)alloc((size_t)256 * 512 * 2);
    __bf16* w2thi = (__bf16*)alloc((size_t)512 * 128 * 2);
    __bf16* w2tlo = (__bf16*)alloc((size_t)512 * 128 * 2);
    float* wsd1 = (float*)alloc(8 * 256 * 4);
    float* wsd2 = (float*)alloc(2 * 512 * 4);
    float* as1_ = (float*)alloc((size_t)N * 4 * 4);
    float* ad1_ = (float*)alloc((size_t)N * 4 * 4);
    float* as2_ = (float*)alloc((size_t)N * 4);
    float* ad2_ = (float*)alloc((size_t)N * 4);
    int*   cnt    = (int*)alloc((size_t)N * 4);
    int*   cur    = (int*)alloc((size_t)N * 4);
    int*   offs   = (int*)alloc((size_t)(N + 1) * 4);
    int*   eid    = (int*)alloc((size_t)ET * 4);
    int*   bsum   = (int*)alloc(256 * 4);
    int*   bofs   = (int*)alloc(256 * 4);
    int*   gstart = (int*)alloc((size_t)(G + 1) * 4);
    float* partial= (float*)alloc((size_t)G * POOL_S * C * 4);
    float* pooled = (float*)alloc((size_t)G * C * 4);

    // ---- CSR build ----
    hipMemsetAsync(cnt, 0, (size_t)N * 4, stream);
    hipMemsetAsync(cur, 0, (size_t)N * 4, stream);
    count_kernel<<<(ET + 255) / 256, 256, 0, stream>>>(ei, cnt, ET, E0);
    scan1<<<NB, 256, 0, stream>>>(cnt, offs, bsum, N);
    scan2<<<1, 256, 0, stream>>>(bsum, bofs, NB, offs + N);
    scan3<<<NB, 256, 0, stream>>>(offs, bofs, N);
    scatter_kernel<<<(ET + 255) / 256, 256, 0, stream>>>(ei, offs, cur, eid, ET, E0);

    // ---- Prep: weights + attention vectors + x conversion ----
    cvtw_kernel<<<(256 * 512 + 512 * 128 + 255) / 256, 256, 0, stream>>>(
        W1, W2, w1thi, w1tlo, w2thi, w2tlo);
    attvec_kernel<<<12, 256, 0, stream>>>(W1, as1w, ad1w, W2, as2w, ad2w, wsd1, wsd2);
    cvtx_kernel<<<N / 4, 256, 0, stream>>>(x, wsd1, xb, as1_, ad1_, N);

    // ---- Layer 1 ----
    gemm_mfma<4, 4, true><<<dim3(HC / 128, (N + 127) / 128), 256, 0, stream>>>(
        xb, w1thi, w1tlo, h1b, N, HC, D);
    aggregate1_kernel<<<N, 128, 0, stream>>>(
        h1b, offs, eid, ei, as1_, ad1_, b1, wsd2, out1b, as2_, ad2_, E0);

    // ---- Layer 2 ----
    gemm_mfma<2, 2, false><<<dim3(C / 64, (N + 63) / 64), 256, 0, stream>>>(
        out1b, w2thi, w2tlo, h2, N, C, HC);
    aggregate2_kernel<<<N, 64, 0, stream>>>(
        h2, offs, eid, ei, as2_, ad2_, b2, out2, E0);

    // ---- Pool + head ----
    gstart_kernel<<<(N + 255) / 256, 256, 0, stream>>>(batch, gstart, N, G);
    pool_stage1<<<dim3(G, POOL_S), C, 0, stream>>>(out2, gstart, partial, C);
    pool_stage2<<<G, C, 0, stream>>>(partial, gstart, pooled, C);
    head_kernel<<<G, 64, 0, stream>>>(pooled, fc1W, fc1b, fc2W, fc2b, out);
}

// Round 4
// 212.669 us; speedup vs baseline: 2.4187x; 1.0768x over previous
//
#include <hip/hip_runtime.h>
#include <hip/hip_bf16.h>
#include <cstdint>
#include <cstddef>

#define NEG_SLOPE 0.2f

typedef __attribute__((ext_vector_type(8))) __bf16 bf16x8;
typedef __attribute__((ext_vector_type(4))) __bf16 bf16x4;
typedef __attribute__((ext_vector_type(2))) __bf16 bf16x2;
typedef __attribute__((ext_vector_type(4))) float  f32x4;

// ---------------------------------------------------------------------------
// No-LDS MFMA GEMM: C[M,N] = A[M,K] @ (Bhi + Blo)[K,N], A bf16 row-major,
// B stored TRANSPOSED [N][K] bf16 (hi/lo split of fp32 weights).
// Block = 256 thr = 4 waves (2x2); wave tile = (16*MF) x (16*NF).
// ---------------------------------------------------------------------------
template<int MF, int NF, bool STORE_BF16>
__global__ __launch_bounds__(256) void gemm_mfma(
    const __bf16* __restrict__ A, const __bf16* __restrict__ Bhi,
    const __bf16* __restrict__ Blo, void* __restrict__ Cout,
    int M, int N, int K)
{
    const int tid  = threadIdx.x;
    const int wave = tid >> 6, lane = tid & 63;
    const int wr = wave >> 1, wc = wave & 1;
    const int rowbase = blockIdx.y * (32 * MF) + wr * (16 * MF);
    const int colbase = blockIdx.x * (32 * NF) + wc * (16 * NF);
    const int l15 = lane & 15, kg = lane >> 4;

    size_t aoff[MF], boff[NF];
    #pragma unroll
    for (int mf = 0; mf < MF; ++mf) {
        int r = rowbase + mf * 16 + l15;
        if (r > M - 1) r = M - 1;              // clamp tail rows (stores guarded)
        aoff[mf] = (size_t)r * K + kg * 8;
    }
    #pragma unroll
    for (int nf = 0; nf < NF; ++nf) {
        int c = colbase + nf * 16 + l15;
        boff[nf] = (size_t)c * K + kg * 8;
    }

    f32x4 acc[MF][NF];
    #pragma unroll
    for (int mf = 0; mf < MF; ++mf)
        #pragma unroll
        for (int nf = 0; nf < NF; ++nf)
            acc[mf][nf] = (f32x4){0.f, 0.f, 0.f, 0.f};

    #pragma unroll 2
    for (int k0 = 0; k0 < K; k0 += 32) {
        bf16x8 af[MF], bh[NF], bl[NF];
        #pragma unroll
        for (int mf = 0; mf < MF; ++mf)
            af[mf] = *(const bf16x8*)(A + aoff[mf] + k0);
        #pragma unroll
        for (int nf = 0; nf < NF; ++nf) {
            bh[nf] = *(const bf16x8*)(Bhi + boff[nf] + k0);
            bl[nf] = *(const bf16x8*)(Blo + boff[nf] + k0);
        }
        #pragma unroll
        for (int mf = 0; mf < MF; ++mf)
            #pragma unroll
            for (int nf = 0; nf < NF; ++nf) {
                acc[mf][nf] = __builtin_amdgcn_mfma_f32_16x16x32_bf16(af[mf], bh[nf], acc[mf][nf], 0, 0, 0);
                acc[mf][nf] = __builtin_amdgcn_mfma_f32_16x16x32_bf16(af[mf], bl[nf], acc[mf][nf], 0, 0, 0);
            }
    }

    #pragma unroll
    for (int mf = 0; mf < MF; ++mf)
        #pragma unroll
        for (int j = 0; j < 4; ++j) {
            int r = rowbase + mf * 16 + kg * 4 + j;
            if (r < M) {
                #pragma unroll
                for (int nf = 0; nf < NF; ++nf) {
                    int c = colbase + nf * 16 + l15;
                    if (STORE_BF16)
                        ((__bf16*)Cout)[(size_t)r * N + c] = (__bf16)acc[mf][nf][j];
                    else
                        ((float*)Cout)[(size_t)r * N + c] = acc[mf][nf][j];
                }
            }
        }
}

// ---------------------------------------------------------------------------
// Weight prep: transpose + hi/lo bf16 split of W1 (256x512) and W2 (512x128).
// ---------------------------------------------------------------------------
__global__ void cvtw_kernel(const float* __restrict__ W1, const float* __restrict__ W2,
                            __bf16* __restrict__ w1thi, __bf16* __restrict__ w1tlo,
                            __bf16* __restrict__ w2thi, __bf16* __restrict__ w2tlo)
{
    int i = blockIdx.x * 256 + threadIdx.x;
    if (i < 256 * 512) {
        int k = i >> 9, n = i & 511;
        float w = W1[i];
        __bf16 hi = (__bf16)w;
        __bf16 lo = (__bf16)(w - (float)hi);
        w1thi[n * 256 + k] = hi;
        w1tlo[n * 256 + k] = lo;
    } else {
        int j = i - 256 * 512;
        if (j < 512 * 128) {
            int k = j >> 7, n = j & 127;
            float w = W2[j];
            __bf16 hi = (__bf16)w;
            __bf16 lo = (__bf16)(w - (float)hi);
            w2thi[n * 512 + k] = hi;
            w2tlo[n * 512 + k] = lo;
        }
    }
}

// ---------------------------------------------------------------------------
// Attention vectors folded through W:  wsd1[v][k] = sum_c W1[k, h*128+c]*a1[h,c]
// (v = 2h + {0:src,1:dst}), wsd2[v][k] = sum_c W2[k,c]*a2[c].
// ---------------------------------------------------------------------------
__global__ void attvec_kernel(const float* __restrict__ W1, const float* __restrict__ as1w,
                              const float* __restrict__ ad1w, const float* __restrict__ W2,
                              const float* __restrict__ as2w, const float* __restrict__ ad2w,
                              float* __restrict__ wsd1, float* __restrict__ wsd2)
{
    int t = blockIdx.x * 256 + threadIdx.x;
    if (t < 2048) {
        int k = t >> 3, v = t & 7, h = v >> 1;
        const float* av = (v & 1) ? (ad1w + h * 128) : (as1w + h * 128);
        float s = 0.f;
        for (int c = 0; c < 128; ++c) s += W1[k * 512 + h * 128 + c] * av[c];
        wsd1[v * 256 + k] = s;
    } else if (t < 3072) {
        int t2 = t - 2048;
        int k = t2 >> 1, v = t2 & 1;
        const float* av = v ? ad2w : as2w;
        float s = 0.f;
        for (int c = 0; c < 128; ++c) s += W2[k * 128 + c] * av[c];
        wsd2[v * 512 + k] = s;
    }
}

// ---------------------------------------------------------------------------
// x -> bf16 + fused layer-1 attention scores (as1/ad1 = x . wsd1[v]).
// ---------------------------------------------------------------------------
__global__ __launch_bounds__(256) void cvtx_kernel(
    const float* __restrict__ x, const float* __restrict__ wsd1,
    __bf16* __restrict__ xb, float* __restrict__ as1_, float* __restrict__ ad1_, int N)
{
    int wave = threadIdx.x >> 6, lane = threadIdx.x & 63;
    int n = blockIdx.x * 4 + wave;
    if (n >= N) return;
    float4 xv = *(const float4*)&x[(size_t)n * 256 + lane * 4];
    bf16x4 xo;
    xo[0] = (__bf16)xv.x; xo[1] = (__bf16)xv.y; xo[2] = (__bf16)xv.z; xo[3] = (__bf16)xv.w;
    *(bf16x4*)&xb[(size_t)n * 256 + lane * 4] = xo;
    float p[8];
    #pragma unroll
    for (int v = 0; v < 8; ++v) {
        float4 wv = *(const float4*)&wsd1[v * 256 + lane * 4];
        p[v] = xv.x * wv.x + xv.y * wv.y + xv.z * wv.z + xv.w * wv.w;
    }
    #pragma unroll
    for (int v = 0; v < 8; ++v)
        #pragma unroll
        for (int s = 1; s < 64; s <<= 1) p[v] += __shfl_xor(p[v], s);
    if (lane == 0) {
        #pragma unroll
        for (int h = 0; h < 4; ++h) {
            as1_[n * 4 + h] = p[2 * h];
            ad1_[n * 4 + h] = p[2 * h + 1];
        }
    }
}

// ---------------------------------------------------------------------------
// CSR build.
// ---------------------------------------------------------------------------
__global__ void count_kernel(const int* __restrict__ ei, int* __restrict__ cnt,
                             int ET, int E0)
{
    int e = blockIdx.x * blockDim.x + threadIdx.x;
    if (e >= ET) return;
    int d = (e < E0) ? ei[E0 + e] : (e - E0);
    atomicAdd(&cnt[d], 1);
}

__global__ void scan1(const int* __restrict__ cnt, int* __restrict__ offs,
                      int* __restrict__ bsum, int n)
{
    __shared__ int tmp[256];
    int t = threadIdx.x;
    int i = blockIdx.x * 256 + t;
    int v = (i < n) ? cnt[i] : 0;
    tmp[t] = v;
    __syncthreads();
    for (int s = 1; s < 256; s <<= 1) {
        int a = (t >= s) ? tmp[t - s] : 0;
        __syncthreads();
        tmp[t] += a;
        __syncthreads();
    }
    if (i < n) offs[i] = tmp[t] - v;
    if (t == 255) bsum[blockIdx.x] = tmp[255];
}

__global__ void scan2(const int* __restrict__ bsum, int* __restrict__ bofs,
                      int B, int* __restrict__ total_dst)
{
    __shared__ int tmp[256];
    int t = threadIdx.x;
    int v = (t < B) ? bsum[t] : 0;
    tmp[t] = v;
    __syncthreads();
    for (int s = 1; s < 256; s <<= 1) {
        int a = (t >= s) ? tmp[t - s] : 0;
        __syncthreads();
        tmp[t] += a;
        __syncthreads();
    }
    if (t < B) bofs[t] = tmp[t] - v;
    if (t == 255) *total_dst = tmp[255];
}

__global__ void scan3(int* __restrict__ offs, const int* __restrict__ bofs, int n)
{
    int i = blockIdx.x * 256 + threadIdx.x;
    if (i < n) offs[i] += bofs[blockIdx.x];
}

__global__ void scatter_kernel(const int* __restrict__ ei, const int* __restrict__ offs,
                               int* __restrict__ cur, int* __restrict__ eid,
                               int ET, int E0)
{
    int e = blockIdx.x * blockDim.x + threadIdx.x;
    if (e >= ET) return;
    int d   = (e < E0) ? ei[E0 + e] : (e - E0);
    int pos = atomicAdd(&cur[d], 1);
    eid[offs[d] + pos] = e;
}

// ---------------------------------------------------------------------------
// Layer-1 aggregate: wave per dst node (4 nodes / 256-thr block). Lane owns
// cols lane*8..lane*8+7 (head = lane>>4). Fused softmax stats + weights +
// weighted sum + bias + relu + bf16 store + layer-2 attention scores.
// Edge loop unrolled 4-wide for memory-level parallelism.
// ---------------------------------------------------------------------------
__global__ __launch_bounds__(256) void aggregate1_kernel(
    const __bf16* __restrict__ h1b, const int* __restrict__ offs,
    const int* __restrict__ eid, const int* __restrict__ ei,
    const float* __restrict__ as1_, const float* __restrict__ ad1_,
    const float* __restrict__ b1, const float* __restrict__ wsd2,
    __bf16* __restrict__ out1b, float* __restrict__ as2_, float* __restrict__ ad2_,
    int E0, int N)
{
    int wave = threadIdx.x >> 6, lane = threadIdx.x & 63;
    int n = blockIdx.x * 4 + wave;
    if (n >= N) return;
    int hd  = lane >> 4;
    int l16 = lane & 15;
    int s0 = offs[n], s1 = offs[n + 1];
    float adn = ad1_[n * 4 + hd];

    float m = -1e30f;
    for (int j = s0 + l16; j < s1; j += 16) {
        int e = eid[j];
        int s = (e < E0) ? ei[e] : (e - E0);
        float v = as1_[s * 4 + hd] + adn;
        v = (v < 0.f) ? NEG_SLOPE * v : v;
        m = fmaxf(m, v);
    }
    #pragma unroll
    for (int t = 1; t < 16; t <<= 1) m = fmaxf(m, __shfl_xor(m, t));
    float den = 0.f;
    for (int j = s0 + l16; j < s1; j += 16) {
        int e = eid[j];
        int s = (e < E0) ? ei[e] : (e - E0);
        float v = as1_[s * 4 + hd] + adn;
        v = (v < 0.f) ? NEG_SLOPE * v : v;
        den += __expf(v - m);
    }
    #pragma unroll
    for (int t = 1; t < 16; t <<= 1) den += __shfl_xor(den, t);
    float inv = 1.f / (den + 1e-16f);

    float a[8] = {0.f, 0.f, 0.f, 0.f, 0.f, 0.f, 0.f, 0.f};
    const __bf16* hbase = h1b + lane * 8;
    int j = s0;
    for (; j + 3 < s1; j += 4) {
        int e0 = eid[j], e1 = eid[j + 1], e2 = eid[j + 2], e3 = eid[j + 3];
        int sA = (e0 < E0) ? ei[e0] : (e0 - E0);
        int sB = (e1 < E0) ? ei[e1] : (e1 - E0);
        int sC = (e2 < E0) ? ei[e2] : (e2 - E0);
        int sD = (e3 < E0) ? ei[e3] : (e3 - E0);
        float vA = as1_[sA * 4 + hd] + adn;
        float vB = as1_[sB * 4 + hd] + adn;
        float vC = as1_[sC * 4 + hd] + adn;
        float vD = as1_[sD * 4 + hd] + adn;
        bf16x8 hA = *(const bf16x8*)(hbase + (size_t)sA * 512);
        bf16x8 hB = *(const bf16x8*)(hbase + (size_t)sB * 512);
        bf16x8 hC = *(const bf16x8*)(hbase + (size_t)sC * 512);
        bf16x8 hD = *(const bf16x8*)(hbase + (size_t)sD * 512);
        vA = (vA < 0.f) ? NEG_SLOPE * vA : vA;
        vB = (vB < 0.f) ? NEG_SLOPE * vB : vB;
        vC = (vC < 0.f) ? NEG_SLOPE * vC : vC;
        vD = (vD < 0.f) ? NEG_SLOPE * vD : vD;
        float wA = __expf(vA - m) * inv;
        float wB = __expf(vB - m) * inv;
        float wC = __expf(vC - m) * inv;
        float wD = __expf(vD - m) * inv;
        #pragma unroll
        for (int i = 0; i < 8; ++i) {
            a[i] = fmaf(wA, (float)hA[i], a[i]);
            a[i] = fmaf(wB, (float)hB[i], a[i]);
            a[i] = fmaf(wC, (float)hC[i], a[i]);
            a[i] = fmaf(wD, (float)hD[i], a[i]);
        }
    }
    for (; j < s1; ++j) {
        int e = eid[j];
        int s = (e < E0) ? ei[e] : (e - E0);
        float v = as1_[s * 4 + hd] + adn;
        v = (v < 0.f) ? NEG_SLOPE * v : v;
        float w = __expf(v - m) * inv;
        bf16x8 hv = *(const bf16x8*)(hbase + (size_t)s * 512);
        #pragma unroll
        for (int i = 0; i < 8; ++i) a[i] = fmaf(w, (float)hv[i], a[i]);
    }

    bf16x8 ov;
    float ps = 0.f, pd = 0.f;
    #pragma unroll
    for (int i = 0; i < 8; ++i) {
        float o = fmaxf(a[i] + b1[lane * 8 + i], 0.f);
        ov[i] = (__bf16)o;
        ps = fmaf(o, wsd2[lane * 8 + i], ps);
        pd = fmaf(o, wsd2[512 + lane * 8 + i], pd);
    }
    *(bf16x8*)&out1b[(size_t)n * 512 + lane * 8] = ov;
    #pragma unroll
    for (int t = 1; t < 64; t <<= 1) {
        ps += __shfl_xor(ps, t);
        pd += __shfl_xor(pd, t);
    }
    if (lane == 0) {
        as2_[n] = ps;
        ad2_[n] = pd;
    }
}

// ---------------------------------------------------------------------------
// Layer-2 aggregate (H=1): wave per dst node, lane owns 2 cols (bf16 h2).
// ---------------------------------------------------------------------------
__global__ __launch_bounds__(256) void aggregate2_kernel(
    const __bf16* __restrict__ h2b, const int* __restrict__ offs,
    const int* __restrict__ eid, const int* __restrict__ ei,
    const float* __restrict__ as2_, const float* __restrict__ ad2_,
    const float* __restrict__ b2, float* __restrict__ out2, int E0, int N)
{
    int wave = threadIdx.x >> 6, lane = threadIdx.x & 63;
    int n = blockIdx.x * 4 + wave;
    if (n >= N) return;
    int s0 = offs[n], s1 = offs[n + 1];
    float adn = ad2_[n];

    float m = -1e30f;
    for (int j = s0 + lane; j < s1; j += 64) {
        int e = eid[j];
        int s = (e < E0) ? ei[e] : (e - E0);
        float v = as2_[s] + adn;
        v = (v < 0.f) ? NEG_SLOPE * v : v;
        m = fmaxf(m, v);
    }
    #pragma unroll
    for (int t = 1; t < 64; t <<= 1) m = fmaxf(m, __shfl_xor(m, t));
    float den = 0.f;
    for (int j = s0 + lane; j < s1; j += 64) {
        int e = eid[j];
        int s = (e < E0) ? ei[e] : (e - E0);
        float v = as2_[s] + adn;
        v = (v < 0.f) ? NEG_SLOPE * v : v;
        den += __expf(v - m);
    }
    #pragma unroll
    for (int t = 1; t < 64; t <<= 1) den += __shfl_xor(den, t);
    float inv = 1.f / (den + 1e-16f);

    float a0 = 0.f, a1 = 0.f;
    const __bf16* hbase = h2b + lane * 2;
    int j = s0;
    for (; j + 3 < s1; j += 4) {
        int e0 = eid[j], e1 = eid[j + 1], e2 = eid[j + 2], e3 = eid[j + 3];
        int sA = (e0 < E0) ? ei[e0] : (e0 - E0);
        int sB = (e1 < E0) ? ei[e1] : (e1 - E0);
        int sC = (e2 < E0) ? ei[e2] : (e2 - E0);
        int sD = (e3 < E0) ? ei[e3] : (e3 - E0);
        float vA = as2_[sA] + adn;
        float vB = as2_[sB] + adn;
        float vC = as2_[sC] + adn;
        float vD = as2_[sD] + adn;
        bf16x2 hA = *(const bf16x2*)(hbase + (size_t)sA * 128);
        bf16x2 hB = *(const bf16x2*)(hbase + (size_t)sB * 128);
        bf16x2 hC = *(const bf16x2*)(hbase + (size_t)sC * 128);
        bf16x2 hD = *(const bf16x2*)(hbase + (size_t)sD * 128);
        vA = (vA < 0.f) ? NEG_SLOPE * vA : vA;
        vB = (vB < 0.f) ? NEG_SLOPE * vB : vB;
        vC = (vC < 0.f) ? NEG_SLOPE * vC : vC;
        vD = (vD < 0.f) ? NEG_SLOPE * vD : vD;
        float wA = __expf(vA - m) * inv;
        float wB = __expf(vB - m) * inv;
        float wC = __expf(vC - m) * inv;
        float wD = __expf(vD - m) * inv;
        a0 = fmaf(wA, (float)hA[0], a0); a1 = fmaf(wA, (float)hA[1], a1);
        a0 = fmaf(wB, (float)hB[0], a0); a1 = fmaf(wB, (float)hB[1], a1);
        a0 = fmaf(wC, (float)hC[0], a0); a1 = fmaf(wC, (float)hC[1], a1);
        a0 = fmaf(wD, (float)hD[0], a0); a1 = fmaf(wD, (float)hD[1], a1);
    }
    for (; j < s1; ++j) {
        int e = eid[j];
        int s = (e < E0) ? ei[e] : (e - E0);
        float v = as2_[s] + adn;
        v = (v < 0.f) ? NEG_SLOPE * v : v;
        float w = __expf(v - m) * inv;
        bf16x2 hv = *(const bf16x2*)(hbase + (size_t)s * 128);
        a0 = fmaf(w, (float)hv[0], a0);
        a1 = fmaf(w, (float)hv[1], a1);
    }
    float2 o;
    o.x = a0 + b2[lane * 2 + 0];
    o.y = a1 + b2[lane * 2 + 1];
    *(float2*)&out2[(size_t)n * 128 + lane * 2] = o;
}

// ---------------------------------------------------------------------------
// Graph segment starts + 2-stage mean pool + FC head.
// ---------------------------------------------------------------------------
__global__ void gstart_kernel(const int* __restrict__ batch, int* __restrict__ gstart,
                              int N, int G)
{
    int n = blockIdx.x * blockDim.x + threadIdx.x;
    if (n >= N) return;
    int b    = batch[n];
    int prev = (n == 0) ? -1 : batch[n - 1];
    for (int g = prev + 1; g <= b; ++g) gstart[g] = n;
    if (n == N - 1) {
        for (int g = b + 1; g <= G; ++g) gstart[g] = N;
    }
}

#define POOL_S 16
__global__ void pool_stage1(const float* __restrict__ out2, const int* __restrict__ gstart,
                            float* __restrict__ partial, int C)
{
    int g = blockIdx.x, slice = blockIdx.y;
    int c = threadIdx.x;
    int s = gstart[g], e = gstart[g + 1];
    int len = e - s;
    int chunk = (len + POOL_S - 1) / POOL_S;
    int n0 = s + slice * chunk;
    int n1 = min(n0 + chunk, e);
    float acc = 0.f;
    for (int n = n0; n < n1; ++n) acc += out2[(size_t)n * C + c];
    partial[((size_t)g * POOL_S + slice) * C + c] = acc;
}

__global__ void pool_stage2(const float* __restrict__ partial, const int* __restrict__ gstart,
                            float* __restrict__ pooled, int C)
{
    int g = blockIdx.x;
    int c = threadIdx.x;
    float acc = 0.f;
    #pragma unroll
    for (int s = 0; s < POOL_S; ++s)
        acc += partial[((size_t)g * POOL_S + s) * C + c];
    float cntf = (float)(gstart[g + 1] - gstart[g]);
    pooled[(size_t)g * C + c] = acc / fmaxf(cntf, 1.0f);
}

__global__ void head_kernel(const float* __restrict__ pooled, const float* __restrict__ fc1W,
                            const float* __restrict__ fc1b, const float* __restrict__ fc2W,
                            const float* __restrict__ fc2b, float* __restrict__ out)
{
    int g = blockIdx.x;
    int j = threadIdx.x;           // 0..63
    float t = 0.f;
    for (int c = 0; c < 128; ++c)
        t += pooled[(size_t)g * 128 + c] * fc1W[c * 64 + j];
    t = fmaxf(t + fc1b[j], 0.f);
    float v = t * fc2W[j];
    #pragma unroll
    for (int s = 32; s > 0; s >>= 1) v += __shfl_down(v, s);
    if (j == 0) out[g] = v + fc2b[0];
}

// ---------------------------------------------------------------------------
extern "C" void kernel_launch(void* const* d_in, const int* in_sizes, int n_in,
                              void* d_out, int out_size, void* d_ws, size_t ws_size,
                              hipStream_t stream)
{
    const float* x    = (const float*)d_in[0];
    const int*   ei   = (const int*)d_in[1];
    const int*   batch= (const int*)d_in[2];
    const float* W1   = (const float*)d_in[3];
    const float* as1w = (const float*)d_in[4];
    const float* ad1w = (const float*)d_in[5];
    const float* b1   = (const float*)d_in[6];
    const float* W2   = (const float*)d_in[7];
    const float* as2w = (const float*)d_in[8];
    const float* ad2w = (const float*)d_in[9];
    const float* b2   = (const float*)d_in[10];
    const float* fc1W = (const float*)d_in[11];
    const float* fc1b = (const float*)d_in[12];
    const float* fc2W = (const float*)d_in[13];
    const float* fc2b = (const float*)d_in[14];
    float* out = (float*)d_out;

    const int D = 256, C = 128, HC = 512, G = 64;
    const int N  = in_sizes[0] / D;        // 20000
    const int E0 = in_sizes[1] / 2;        // 160000
    const int ET = E0 + N;
    const int NB = (N + 255) / 256;

    char* p = (char*)d_ws;
    auto alloc = [&](size_t bytes) -> char* {
        char* r = p;
        p += (bytes + 255) & ~(size_t)255;
        return r;
    };
    __bf16* xb    = (__bf16*)alloc((size_t)N * D * 2);
    __bf16* h1b   = (__bf16*)alloc((size_t)N * HC * 2);
    __bf16* out1b = (__bf16*)alloc((size_t)N * HC * 2);
    __bf16* h2b   = (__bf16*)alloc((size_t)N * C * 2);
    float*  out2  = (float*)alloc((size_t)N * C * 4);
    __bf16* w1thi = (__bf16*)alloc((size_t)256 * 512 * 2);
    __bf16* w1tlo = (__bf16*)alloc((size_t)256 * 512 * 2);
    __bf16* w2thi = (__bf16*)alloc((size_t)512 * 128 * 2);
    __bf16* w2tlo = (__bf16*)alloc((size_t)512 * 128 * 2);
    float* wsd1 = (float*)alloc(8 * 256 * 4);
    float* wsd2 = (float*)alloc(2 * 512 * 4);
    float* as1_ = (float*)alloc((size_t)N * 4 * 4);
    float* ad1_ = (float*)alloc((size_t)N * 4 * 4);
    float* as2_ = (float*)alloc((size_t)N * 4);
    float* ad2_ = (float*)alloc((size_t)N * 4);
    int*   cnt    = (int*)alloc((size_t)N * 4);
    int*   cur    = (int*)alloc((size_t)N * 4);
    int*   offs   = (int*)alloc((size_t)(N + 1) * 4);
    int*   eid    = (int*)alloc((size_t)ET * 4);
    int*   bsum   = (int*)alloc(256 * 4);
    int*   bofs   = (int*)alloc(256 * 4);
    int*   gstart = (int*)alloc((size_t)(G + 1) * 4);
    float* partial= (float*)alloc((size_t)G * POOL_S * C * 4);
    float* pooled = (float*)alloc((size_t)G * C * 4);

    // ---- CSR build ----
    hipMemsetAsync(cnt, 0, (size_t)N * 4, stream);
    hipMemsetAsync(cur, 0, (size_t)N * 4, stream);
    count_kernel<<<(ET + 255) / 256, 256, 0, stream>>>(ei, cnt, ET, E0);
    scan1<<<NB, 256, 0, stream>>>(cnt, offs, bsum, N);
    scan2<<<1, 256, 0, stream>>>(bsum, bofs, NB, offs + N);
    scan3<<<NB, 256, 0, stream>>>(offs, bofs, N);
    scatter_kernel<<<(ET + 255) / 256, 256, 0, stream>>>(ei, offs, cur, eid, ET, E0);

    // ---- Prep: weights + attention vectors + x conversion ----
    cvtw_kernel<<<(256 * 512 + 512 * 128 + 255) / 256, 256, 0, stream>>>(
        W1, W2, w1thi, w1tlo, w2thi, w2tlo);
    attvec_kernel<<<12, 256, 0, stream>>>(W1, as1w, ad1w, W2, as2w, ad2w, wsd1, wsd2);
    cvtx_kernel<<<N / 4, 256, 0, stream>>>(x, wsd1, xb, as1_, ad1_, N);

    // ---- Layer 1 ----
    gemm_mfma<4, 4, true><<<dim3(HC / 128, (N + 127) / 128), 256, 0, stream>>>(
        xb, w1thi, w1tlo, h1b, N, HC, D);
    aggregate1_kernel<<<(N + 3) / 4, 256, 0, stream>>>(
        h1b, offs, eid, ei, as1_, ad1_, b1, wsd2, out1b, as2_, ad2_, E0, N);

    // ---- Layer 2 ----
    gemm_mfma<2, 2, true><<<dim3(C / 64, (N + 63) / 64), 256, 0, stream>>>(
        out1b, w2thi, w2tlo, h2b, N, C, HC);
    aggregate2_kernel<<<(N + 3) / 4, 256, 0, stream>>>(
        h2b, offs, eid, ei, as2_, ad2_, b2, out2, E0, N);

    // ---- Pool + head ----
    gstart_kernel<<<(N + 255) / 256, 256, 0, stream>>>(batch, gstart, N, G);
    pool_stage1<<<dim3(G, POOL_S), C, 0, stream>>>(out2, gstart, partial, C);
    pool_stage2<<<G, C, 0, stream>>>(partial, gstart, pooled, C);
    head_kernel<<<G, 64, 0, stream>>>(pooled, fc1W, fc1b, fc2W, fc2b, out);
}

// Round 5
// 201.498 us; speedup vs baseline: 2.5528x; 1.0554x over previous
//
#include <hip/hip_runtime.h>
#include <hip/hip_bf16.h>
#include <cstdint>
#include <cstddef>

#define NEG_SLOPE 0.2f

typedef __attribute__((ext_vector_type(8))) __bf16 bf16x8;
typedef __attribute__((ext_vector_type(4))) __bf16 bf16x4;
typedef __attribute__((ext_vector_type(2))) __bf16 bf16x2;
typedef __attribute__((ext_vector_type(4))) float  f32x4;

// ---------------------------------------------------------------------------
// No-LDS MFMA GEMM: C[M,N] = A[M,K] @ (Bhi + Blo)[K,N], A bf16 row-major,
// B stored TRANSPOSED [N][K] bf16 (hi/lo split of fp32 weights).
// Block = 256 thr = 4 waves (2x2); wave tile = (16*MF) x (16*NF).
// ---------------------------------------------------------------------------
template<int MF, int NF, bool STORE_BF16>
__global__ __launch_bounds__(256) void gemm_mfma(
    const __bf16* __restrict__ A, const __bf16* __restrict__ Bhi,
    const __bf16* __restrict__ Blo, void* __restrict__ Cout,
    int M, int N, int K)
{
    const int tid  = threadIdx.x;
    const int wave = tid >> 6, lane = tid & 63;
    const int wr = wave >> 1, wc = wave & 1;
    const int rowbase = blockIdx.y * (32 * MF) + wr * (16 * MF);
    const int colbase = blockIdx.x * (32 * NF) + wc * (16 * NF);
    const int l15 = lane & 15, kg = lane >> 4;

    size_t aoff[MF], boff[NF];
    #pragma unroll
    for (int mf = 0; mf < MF; ++mf) {
        int r = rowbase + mf * 16 + l15;
        if (r > M - 1) r = M - 1;              // clamp tail rows (stores guarded)
        aoff[mf] = (size_t)r * K + kg * 8;
    }
    #pragma unroll
    for (int nf = 0; nf < NF; ++nf) {
        int c = colbase + nf * 16 + l15;
        boff[nf] = (size_t)c * K + kg * 8;
    }

    f32x4 acc[MF][NF];
    #pragma unroll
    for (int mf = 0; mf < MF; ++mf)
        #pragma unroll
        for (int nf = 0; nf < NF; ++nf)
            acc[mf][nf] = (f32x4){0.f, 0.f, 0.f, 0.f};

    #pragma unroll 2
    for (int k0 = 0; k0 < K; k0 += 32) {
        bf16x8 af[MF], bh[NF], bl[NF];
        #pragma unroll
        for (int mf = 0; mf < MF; ++mf)
            af[mf] = *(const bf16x8*)(A + aoff[mf] + k0);
        #pragma unroll
        for (int nf = 0; nf < NF; ++nf) {
            bh[nf] = *(const bf16x8*)(Bhi + boff[nf] + k0);
            bl[nf] = *(const bf16x8*)(Blo + boff[nf] + k0);
        }
        #pragma unroll
        for (int mf = 0; mf < MF; ++mf)
            #pragma unroll
            for (int nf = 0; nf < NF; ++nf) {
                acc[mf][nf] = __builtin_amdgcn_mfma_f32_16x16x32_bf16(af[mf], bh[nf], acc[mf][nf], 0, 0, 0);
                acc[mf][nf] = __builtin_amdgcn_mfma_f32_16x16x32_bf16(af[mf], bl[nf], acc[mf][nf], 0, 0, 0);
            }
    }

    #pragma unroll
    for (int mf = 0; mf < MF; ++mf)
        #pragma unroll
        for (int j = 0; j < 4; ++j) {
            int r = rowbase + mf * 16 + kg * 4 + j;
            if (r < M) {
                #pragma unroll
                for (int nf = 0; nf < NF; ++nf) {
                    int c = colbase + nf * 16 + l15;
                    if (STORE_BF16)
                        ((__bf16*)Cout)[(size_t)r * N + c] = (__bf16)acc[mf][nf][j];
                    else
                        ((float*)Cout)[(size_t)r * N + c] = acc[mf][nf][j];
                }
            }
        }
}

// ---------------------------------------------------------------------------
// Fused prep: W1/W2 transpose + hi/lo bf16 split, attention vectors folded
// through W, graph-segment starts, and cnt zeroing. Range-dispatched by
// global thread id (no syncs inside, all parts independent).
//   [0, 131072)           cvtw W1
//   [131072, 196608)      cvtw W2
//   [196608, 199680)      attvec (3072)
//   [199680, 199680+N)    gstart
//   [199680+N, 199680+2N) cnt zero
// ---------------------------------------------------------------------------
__global__ void prep_kernel(const float* __restrict__ W1, const float* __restrict__ W2,
                            const float* __restrict__ as1w, const float* __restrict__ ad1w,
                            const float* __restrict__ as2w, const float* __restrict__ ad2w,
                            const int* __restrict__ batch,
                            __bf16* __restrict__ w1thi, __bf16* __restrict__ w1tlo,
                            __bf16* __restrict__ w2thi, __bf16* __restrict__ w2tlo,
                            float* __restrict__ wsd1, float* __restrict__ wsd2,
                            int* __restrict__ gstart, int* __restrict__ cnt,
                            int N, int G)
{
    int t = blockIdx.x * 256 + threadIdx.x;
    if (t < 131072) {
        int i = t;
        int k = i >> 9, n = i & 511;
        float w = W1[i];
        __bf16 hi = (__bf16)w;
        __bf16 lo = (__bf16)(w - (float)hi);
        w1thi[n * 256 + k] = hi;
        w1tlo[n * 256 + k] = lo;
    } else if (t < 196608) {
        int j = t - 131072;
        int k = j >> 7, n = j & 127;
        float w = W2[j];
        __bf16 hi = (__bf16)w;
        __bf16 lo = (__bf16)(w - (float)hi);
        w2thi[n * 512 + k] = hi;
        w2tlo[n * 512 + k] = lo;
    } else if (t < 199680) {
        int t2 = t - 196608;
        if (t2 < 2048) {
            int k = t2 >> 3, v = t2 & 7, h = v >> 1;
            const float* av = (v & 1) ? (ad1w + h * 128) : (as1w + h * 128);
            float s = 0.f;
            for (int c = 0; c < 128; ++c) s += W1[k * 512 + h * 128 + c] * av[c];
            wsd1[v * 256 + k] = s;
        } else {
            int t3 = t2 - 2048;
            int k = t3 >> 1, v = t3 & 1;
            const float* av = v ? ad2w : as2w;
            float s = 0.f;
            for (int c = 0; c < 128; ++c) s += W2[k * 128 + c] * av[c];
            wsd2[v * 512 + k] = s;
        }
    } else if (t < 199680 + N) {
        int n = t - 199680;
        int b    = batch[n];
        int prev = (n == 0) ? -1 : batch[n - 1];
        for (int g = prev + 1; g <= b; ++g) gstart[g] = n;
        if (n == N - 1) {
            for (int g = b + 1; g <= G; ++g) gstart[g] = N;
        }
    } else if (t < 199680 + 2 * N) {
        cnt[t - 199680 - N] = 0;
    }
}

// ---------------------------------------------------------------------------
// x -> bf16 + fused layer-1 attention scores (as1/ad1 = x . wsd1[v]).
// ---------------------------------------------------------------------------
__global__ __launch_bounds__(256) void cvtx_kernel(
    const float* __restrict__ x, const float* __restrict__ wsd1,
    __bf16* __restrict__ xb, float* __restrict__ as1_, float* __restrict__ ad1_, int N)
{
    int wave = threadIdx.x >> 6, lane = threadIdx.x & 63;
    int n = blockIdx.x * 4 + wave;
    if (n >= N) return;
    float4 xv = *(const float4*)&x[(size_t)n * 256 + lane * 4];
    bf16x4 xo;
    xo[0] = (__bf16)xv.x; xo[1] = (__bf16)xv.y; xo[2] = (__bf16)xv.z; xo[3] = (__bf16)xv.w;
    *(bf16x4*)&xb[(size_t)n * 256 + lane * 4] = xo;
    float p[8];
    #pragma unroll
    for (int v = 0; v < 8; ++v) {
        float4 wv = *(const float4*)&wsd1[v * 256 + lane * 4];
        p[v] = xv.x * wv.x + xv.y * wv.y + xv.z * wv.z + xv.w * wv.w;
    }
    #pragma unroll
    for (int v = 0; v < 8; ++v)
        #pragma unroll
        for (int s = 1; s < 64; s <<= 1) p[v] += __shfl_xor(p[v], s);
    if (lane == 0) {
        #pragma unroll
        for (int h = 0; h < 4; ++h) {
            as1_[n * 4 + h] = p[2 * h];
            ad1_[n * 4 + h] = p[2 * h + 1];
        }
    }
}

// ---------------------------------------------------------------------------
// CSR build.
// ---------------------------------------------------------------------------
__global__ void count_kernel(const int* __restrict__ ei, int* __restrict__ cnt,
                             int ET, int E0)
{
    int e = blockIdx.x * blockDim.x + threadIdx.x;
    if (e >= ET) return;
    int d = (e < E0) ? ei[E0 + e] : (e - E0);
    atomicAdd(&cnt[d], 1);
}

__global__ void scan1(const int* __restrict__ cnt, int* __restrict__ offs,
                      int* __restrict__ bsum, int n)
{
    __shared__ int tmp[256];
    int t = threadIdx.x;
    int i = blockIdx.x * 256 + t;
    int v = (i < n) ? cnt[i] : 0;
    tmp[t] = v;
    __syncthreads();
    for (int s = 1; s < 256; s <<= 1) {
        int a = (t >= s) ? tmp[t - s] : 0;
        __syncthreads();
        tmp[t] += a;
        __syncthreads();
    }
    if (i < n) offs[i] = tmp[t] - v;
    if (t == 255) bsum[blockIdx.x] = tmp[255];
}

__global__ void scan2(const int* __restrict__ bsum, int* __restrict__ bofs,
                      int B, int* __restrict__ total_dst)
{
    __shared__ int tmp[256];
    int t = threadIdx.x;
    int v = (t < B) ? bsum[t] : 0;
    tmp[t] = v;
    __syncthreads();
    for (int s = 1; s < 256; s <<= 1) {
        int a = (t >= s) ? tmp[t - s] : 0;
        __syncthreads();
        tmp[t] += a;
        __syncthreads();
    }
    if (t < B) bofs[t] = tmp[t] - v;
    if (t == 255) *total_dst = tmp[255];
}

// scan3 also initializes cur[i] = offs[i] (running cursor for scatter).
__global__ void scan3(int* __restrict__ offs, const int* __restrict__ bofs,
                      int* __restrict__ cur, int n)
{
    int i = blockIdx.x * 256 + threadIdx.x;
    if (i < n) {
        int o = offs[i] + bofs[blockIdx.x];
        offs[i] = o;
        cur[i]  = o;
    }
}

__global__ void scatter_kernel(const int* __restrict__ ei, int* __restrict__ cur,
                               int* __restrict__ eid, int ET, int E0)
{
    int e = blockIdx.x * blockDim.x + threadIdx.x;
    if (e >= ET) return;
    int d   = (e < E0) ? ei[E0 + e] : (e - E0);
    int pos = atomicAdd(&cur[d], 1);
    eid[pos] = e;
}

// ---------------------------------------------------------------------------
// Layer-1 aggregate: wave per dst node (4 nodes / 256-thr block). Lane owns
// cols lane*8..lane*8+7 (head = lane>>4). Fused softmax stats + weights +
// weighted sum + bias + relu + bf16 store + layer-2 attention scores.
// Edge loop unrolled 4-wide for memory-level parallelism.
// ---------------------------------------------------------------------------
__global__ __launch_bounds__(256) void aggregate1_kernel(
    const __bf16* __restrict__ h1b, const int* __restrict__ offs,
    const int* __restrict__ eid, const int* __restrict__ ei,
    const float* __restrict__ as1_, const float* __restrict__ ad1_,
    const float* __restrict__ b1, const float* __restrict__ wsd2,
    __bf16* __restrict__ out1b, float* __restrict__ as2_, float* __restrict__ ad2_,
    int E0, int N)
{
    int wave = threadIdx.x >> 6, lane = threadIdx.x & 63;
    int n = blockIdx.x * 4 + wave;
    if (n >= N) return;
    int hd  = lane >> 4;
    int l16 = lane & 15;
    int s0 = offs[n], s1 = offs[n + 1];
    float adn = ad1_[n * 4 + hd];

    float m = -1e30f;
    for (int j = s0 + l16; j < s1; j += 16) {
        int e = eid[j];
        int s = (e < E0) ? ei[e] : (e - E0);
        float v = as1_[s * 4 + hd] + adn;
        v = (v < 0.f) ? NEG_SLOPE * v : v;
        m = fmaxf(m, v);
    }
    #pragma unroll
    for (int t = 1; t < 16; t <<= 1) m = fmaxf(m, __shfl_xor(m, t));
    float den = 0.f;
    for (int j = s0 + l16; j < s1; j += 16) {
        int e = eid[j];
        int s = (e < E0) ? ei[e] : (e - E0);
        float v = as1_[s * 4 + hd] + adn;
        v = (v < 0.f) ? NEG_SLOPE * v : v;
        den += __expf(v - m);
    }
    #pragma unroll
    for (int t = 1; t < 16; t <<= 1) den += __shfl_xor(den, t);
    float inv = 1.f / (den + 1e-16f);

    float a[8] = {0.f, 0.f, 0.f, 0.f, 0.f, 0.f, 0.f, 0.f};
    const __bf16* hbase = h1b + lane * 8;
    int j = s0;
    for (; j + 3 < s1; j += 4) {
        int e0 = eid[j], e1 = eid[j + 1], e2 = eid[j + 2], e3 = eid[j + 3];
        int sA = (e0 < E0) ? ei[e0] : (e0 - E0);
        int sB = (e1 < E0) ? ei[e1] : (e1 - E0);
        int sC = (e2 < E0) ? ei[e2] : (e2 - E0);
        int sD = (e3 < E0) ? ei[e3] : (e3 - E0);
        float vA = as1_[sA * 4 + hd] + adn;
        float vB = as1_[sB * 4 + hd] + adn;
        float vC = as1_[sC * 4 + hd] + adn;
        float vD = as1_[sD * 4 + hd] + adn;
        bf16x8 hA = *(const bf16x8*)(hbase + (size_t)sA * 512);
        bf16x8 hB = *(const bf16x8*)(hbase + (size_t)sB * 512);
        bf16x8 hC = *(const bf16x8*)(hbase + (size_t)sC * 512);
        bf16x8 hD = *(const bf16x8*)(hbase + (size_t)sD * 512);
        vA = (vA < 0.f) ? NEG_SLOPE * vA : vA;
        vB = (vB < 0.f) ? NEG_SLOPE * vB : vB;
        vC = (vC < 0.f) ? NEG_SLOPE * vC : vC;
        vD = (vD < 0.f) ? NEG_SLOPE * vD : vD;
        float wA = __expf(vA - m) * inv;
        float wB = __expf(vB - m) * inv;
        float wC = __expf(vC - m) * inv;
        float wD = __expf(vD - m) * inv;
        #pragma unroll
        for (int i = 0; i < 8; ++i) {
            a[i] = fmaf(wA, (float)hA[i], a[i]);
            a[i] = fmaf(wB, (float)hB[i], a[i]);
            a[i] = fmaf(wC, (float)hC[i], a[i]);
            a[i] = fmaf(wD, (float)hD[i], a[i]);
        }
    }
    for (; j < s1; ++j) {
        int e = eid[j];
        int s = (e < E0) ? ei[e] : (e - E0);
        float v = as1_[s * 4 + hd] + adn;
        v = (v < 0.f) ? NEG_SLOPE * v : v;
        float w = __expf(v - m) * inv;
        bf16x8 hv = *(const bf16x8*)(hbase + (size_t)s * 512);
        #pragma unroll
        for (int i = 0; i < 8; ++i) a[i] = fmaf(w, (float)hv[i], a[i]);
    }

    bf16x8 ov;
    float ps = 0.f, pd = 0.f;
    #pragma unroll
    for (int i = 0; i < 8; ++i) {
        float o = fmaxf(a[i] + b1[lane * 8 + i], 0.f);
        ov[i] = (__bf16)o;
        ps = fmaf(o, wsd2[lane * 8 + i], ps);
        pd = fmaf(o, wsd2[512 + lane * 8 + i], pd);
    }
    *(bf16x8*)&out1b[(size_t)n * 512 + lane * 8] = ov;
    #pragma unroll
    for (int t = 1; t < 64; t <<= 1) {
        ps += __shfl_xor(ps, t);
        pd += __shfl_xor(pd, t);
    }
    if (lane == 0) {
        as2_[n] = ps;
        ad2_[n] = pd;
    }
}

// ---------------------------------------------------------------------------
// Layer-2 aggregate (H=1): wave per dst node, lane owns 2 cols (bf16 h2).
// ---------------------------------------------------------------------------
__global__ __launch_bounds__(256) void aggregate2_kernel(
    const __bf16* __restrict__ h2b, const int* __restrict__ offs,
    const int* __restrict__ eid, const int* __restrict__ ei,
    const float* __restrict__ as2_, const float* __restrict__ ad2_,
    const float* __restrict__ b2, float* __restrict__ out2, int E0, int N)
{
    int wave = threadIdx.x >> 6, lane = threadIdx.x & 63;
    int n = blockIdx.x * 4 + wave;
    if (n >= N) return;
    int s0 = offs[n], s1 = offs[n + 1];
    float adn = ad2_[n];

    float m = -1e30f;
    for (int j = s0 + lane; j < s1; j += 64) {
        int e = eid[j];
        int s = (e < E0) ? ei[e] : (e - E0);
        float v = as2_[s] + adn;
        v = (v < 0.f) ? NEG_SLOPE * v : v;
        m = fmaxf(m, v);
    }
    #pragma unroll
    for (int t = 1; t < 64; t <<= 1) m = fmaxf(m, __shfl_xor(m, t));
    float den = 0.f;
    for (int j = s0 + lane; j < s1; j += 64) {
        int e = eid[j];
        int s = (e < E0) ? ei[e] : (e - E0);
        float v = as2_[s] + adn;
        v = (v < 0.f) ? NEG_SLOPE * v : v;
        den += __expf(v - m);
    }
    #pragma unroll
    for (int t = 1; t < 64; t <<= 1) den += __shfl_xor(den, t);
    float inv = 1.f / (den + 1e-16f);

    float a0 = 0.f, a1 = 0.f;
    const __bf16* hbase = h2b + lane * 2;
    int j = s0;
    for (; j + 3 < s1; j += 4) {
        int e0 = eid[j], e1 = eid[j + 1], e2 = eid[j + 2], e3 = eid[j + 3];
        int sA = (e0 < E0) ? ei[e0] : (e0 - E0);
        int sB = (e1 < E0) ? ei[e1] : (e1 - E0);
        int sC = (e2 < E0) ? ei[e2] : (e2 - E0);
        int sD = (e3 < E0) ? ei[e3] : (e3 - E0);
        float vA = as2_[sA] + adn;
        float vB = as2_[sB] + adn;
        float vC = as2_[sC] + adn;
        float vD = as2_[sD] + adn;
        bf16x2 hA = *(const bf16x2*)(hbase + (size_t)sA * 128);
        bf16x2 hB = *(const bf16x2*)(hbase + (size_t)sB * 128);
        bf16x2 hC = *(const bf16x2*)(hbase + (size_t)sC * 128);
        bf16x2 hD = *(const bf16x2*)(hbase + (size_t)sD * 128);
        vA = (vA < 0.f) ? NEG_SLOPE * vA : vA;
        vB = (vB < 0.f) ? NEG_SLOPE * vB : vB;
        vC = (vC < 0.f) ? NEG_SLOPE * vC : vC;
        vD = (vD < 0.f) ? NEG_SLOPE * vD : vD;
        float wA = __expf(vA - m) * inv;
        float wB = __expf(vB - m) * inv;
        float wC = __expf(vC - m) * inv;
        float wD = __expf(vD - m) * inv;
        a0 = fmaf(wA, (float)hA[0], a0); a1 = fmaf(wA, (float)hA[1], a1);
        a0 = fmaf(wB, (float)hB[0], a0); a1 = fmaf(wB, (float)hB[1], a1);
        a0 = fmaf(wC, (float)hC[0], a0); a1 = fmaf(wC, (float)hC[1], a1);
        a0 = fmaf(wD, (float)hD[0], a0); a1 = fmaf(wD, (float)hD[1], a1);
    }
    for (; j < s1; ++j) {
        int e = eid[j];
        int s = (e < E0) ? ei[e] : (e - E0);
        float v = as2_[s] + adn;
        v = (v < 0.f) ? NEG_SLOPE * v : v;
        float w = __expf(v - m) * inv;
        bf16x2 hv = *(const bf16x2*)(hbase + (size_t)s * 128);
        a0 = fmaf(w, (float)hv[0], a0);
        a1 = fmaf(w, (float)hv[1], a1);
    }
    float2 o;
    o.x = a0 + b2[lane * 2 + 0];
    o.y = a1 + b2[lane * 2 + 1];
    *(float2*)&out2[(size_t)n * 128 + lane * 2] = o;
}

// ---------------------------------------------------------------------------
// 2-stage mean pool + FC head.
// ---------------------------------------------------------------------------
#define POOL_S 16
__global__ void pool_stage1(const float* __restrict__ out2, const int* __restrict__ gstart,
                            float* __restrict__ partial, int C)
{
    int g = blockIdx.x, slice = blockIdx.y;
    int c = threadIdx.x;
    int s = gstart[g], e = gstart[g + 1];
    int len = e - s;
    int chunk = (len + POOL_S - 1) / POOL_S;
    int n0 = s + slice * chunk;
    int n1 = min(n0 + chunk, e);
    float acc = 0.f;
    for (int n = n0; n < n1; ++n) acc += out2[(size_t)n * C + c];
    partial[((size_t)g * POOL_S + slice) * C + c] = acc;
}

__global__ void pool_stage2(const float* __restrict__ partial, const int* __restrict__ gstart,
                            float* __restrict__ pooled, int C)
{
    int g = blockIdx.x;
    int c = threadIdx.x;
    float acc = 0.f;
    #pragma unroll
    for (int s = 0; s < POOL_S; ++s)
        acc += partial[((size_t)g * POOL_S + s) * C + c];
    float cntf = (float)(gstart[g + 1] - gstart[g]);
    pooled[(size_t)g * C + c] = acc / fmaxf(cntf, 1.0f);
}

__global__ void head_kernel(const float* __restrict__ pooled, const float* __restrict__ fc1W,
                            const float* __restrict__ fc1b, const float* __restrict__ fc2W,
                            const float* __restrict__ fc2b, float* __restrict__ out)
{
    int g = blockIdx.x;
    int j = threadIdx.x;           // 0..63
    float t = 0.f;
    for (int c = 0; c < 128; ++c)
        t += pooled[(size_t)g * 128 + c] * fc1W[c * 64 + j];
    t = fmaxf(t + fc1b[j], 0.f);
    float v = t * fc2W[j];
    #pragma unroll
    for (int s = 32; s > 0; s >>= 1) v += __shfl_down(v, s);
    if (j == 0) out[g] = v + fc2b[0];
}

// ---------------------------------------------------------------------------
extern "C" void kernel_launch(void* const* d_in, const int* in_sizes, int n_in,
                              void* d_out, int out_size, void* d_ws, size_t ws_size,
                              hipStream_t stream)
{
    const float* x    = (const float*)d_in[0];
    const int*   ei   = (const int*)d_in[1];
    const int*   batch= (const int*)d_in[2];
    const float* W1   = (const float*)d_in[3];
    const float* as1w = (const float*)d_in[4];
    const float* ad1w = (const float*)d_in[5];
    const float* b1   = (const float*)d_in[6];
    const float* W2   = (const float*)d_in[7];
    const float* as2w = (const float*)d_in[8];
    const float* ad2w = (const float*)d_in[9];
    const float* b2   = (const float*)d_in[10];
    const float* fc1W = (const float*)d_in[11];
    const float* fc1b = (const float*)d_in[12];
    const float* fc2W = (const float*)d_in[13];
    const float* fc2b = (const float*)d_in[14];
    float* out = (float*)d_out;

    const int D = 256, C = 128, HC = 512, G = 64;
    const int N  = in_sizes[0] / D;        // 20000
    const int E0 = in_sizes[1] / 2;        // 160000
    const int ET = E0 + N;
    const int NB = (N + 255) / 256;

    char* p = (char*)d_ws;
    auto alloc = [&](size_t bytes) -> char* {
        char* r = p;
        p += (bytes + 255) & ~(size_t)255;
        return r;
    };
    __bf16* xb    = (__bf16*)alloc((size_t)N * D * 2);
    __bf16* h1b   = (__bf16*)alloc((size_t)N * HC * 2);
    __bf16* out1b = (__bf16*)alloc((size_t)N * HC * 2);
    __bf16* h2b   = (__bf16*)alloc((size_t)N * C * 2);
    float*  out2  = (float*)alloc((size_t)N * C * 4);
    __bf16* w1thi = (__bf16*)alloc((size_t)256 * 512 * 2);
    __bf16* w1tlo = (__bf16*)alloc((size_t)256 * 512 * 2);
    __bf16* w2thi = (__bf16*)alloc((size_t)512 * 128 * 2);
    __bf16* w2tlo = (__bf16*)alloc((size_t)512 * 128 * 2);
    float* wsd1 = (float*)alloc(8 * 256 * 4);
    float* wsd2 = (float*)alloc(2 * 512 * 4);
    float* as1_ = (float*)alloc((size_t)N * 4 * 4);
    float* ad1_ = (float*)alloc((size_t)N * 4 * 4);
    float* as2_ = (float*)alloc((size_t)N * 4);
    float* ad2_ = (float*)alloc((size_t)N * 4);
    int*   cnt    = (int*)alloc((size_t)N * 4);
    int*   cur    = (int*)alloc((size_t)N * 4);
    int*   offs   = (int*)alloc((size_t)(N + 1) * 4);
    int*   eid    = (int*)alloc((size_t)ET * 4);
    int*   bsum   = (int*)alloc(256 * 4);
    int*   bofs   = (int*)alloc(256 * 4);
    int*   gstart = (int*)alloc((size_t)(G + 1) * 4);
    float* partial= (float*)alloc((size_t)G * POOL_S * C * 4);
    float* pooled = (float*)alloc((size_t)G * C * 4);

    // ---- Fused prep: cvtw + attvec + gstart + cnt zero (no memsets!) ----
    {
        int total = 199680 + 2 * N;
        prep_kernel<<<(total + 255) / 256, 256, 0, stream>>>(
            W1, W2, as1w, ad1w, as2w, ad2w, batch,
            w1thi, w1tlo, w2thi, w2tlo, wsd1, wsd2, gstart, cnt, N, G);
    }

    // ---- CSR build ----
    count_kernel<<<(ET + 255) / 256, 256, 0, stream>>>(ei, cnt, ET, E0);
    scan1<<<NB, 256, 0, stream>>>(cnt, offs, bsum, N);
    scan2<<<1, 256, 0, stream>>>(bsum, bofs, NB, offs + N);
    scan3<<<NB, 256, 0, stream>>>(offs, bofs, cur, N);
    scatter_kernel<<<(ET + 255) / 256, 256, 0, stream>>>(ei, cur, eid, ET, E0);

    // ---- x conversion + layer-1 attention scores ----
    cvtx_kernel<<<N / 4, 256, 0, stream>>>(x, wsd1, xb, as1_, ad1_, N);

    // ---- Layer 1 ----
    gemm_mfma<4, 4, true><<<dim3(HC / 128, (N + 127) / 128), 256, 0, stream>>>(
        xb, w1thi, w1tlo, h1b, N, HC, D);
    aggregate1_kernel<<<(N + 3) / 4, 256, 0, stream>>>(
        h1b, offs, eid, ei, as1_, ad1_, b1, wsd2, out1b, as2_, ad2_, E0, N);

    // ---- Layer 2 ----
    gemm_mfma<2, 2, true><<<dim3(C / 64, (N + 63) / 64), 256, 0, stream>>>(
        out1b, w2thi, w2tlo, h2b, N, C, HC);
    aggregate2_kernel<<<(N + 3) / 4, 256, 0, stream>>>(
        h2b, offs, eid, ei, as2_, ad2_, b2, out2, E0, N);

    // ---- Pool + head ----
    pool_stage1<<<dim3(G, POOL_S), C, 0, stream>>>(out2, gstart, partial, C);
    pool_stage2<<<G, C, 0, stream>>>(partial, gstart, pooled, C);
    head_kernel<<<G, 64, 0, stream>>>(pooled, fc1W, fc1b, fc2W, fc2b, out);
}

// Round 6
// 196.732 us; speedup vs baseline: 2.6147x; 1.0242x over previous
//
#include <hip/hip_runtime.h>
#include <hip/hip_bf16.h>
#include <cstdint>
#include <cstddef>

#define NEG_SLOPE 0.2f

typedef __attribute__((ext_vector_type(8))) __bf16 bf16x8;
typedef __attribute__((ext_vector_type(4))) __bf16 bf16x4;
typedef __attribute__((ext_vector_type(2))) __bf16 bf16x2;
typedef __attribute__((ext_vector_type(4))) float  f32x4;

// ---------------------------------------------------------------------------
// No-LDS MFMA GEMM: C[M,N] = A[M,K] @ B[K,N], A bf16 row-major,
// B stored TRANSPOSED [N][K] bf16. Block = 256 thr = 4 waves (2x2);
// wave tile = (16*MF) x (16*NF). Fragments loaded straight from global.
// ---------------------------------------------------------------------------
template<int MF, int NF, bool STORE_BF16>
__global__ __launch_bounds__(256) void gemm_mfma(
    const __bf16* __restrict__ A, const __bf16* __restrict__ Bt,
    void* __restrict__ Cout, int M, int N, int K)
{
    const int tid  = threadIdx.x;
    const int wave = tid >> 6, lane = tid & 63;
    const int wr = wave >> 1, wc = wave & 1;
    const int rowbase = blockIdx.y * (32 * MF) + wr * (16 * MF);
    const int colbase = blockIdx.x * (32 * NF) + wc * (16 * NF);
    const int l15 = lane & 15, kg = lane >> 4;

    size_t aoff[MF], boff[NF];
    #pragma unroll
    for (int mf = 0; mf < MF; ++mf) {
        int r = rowbase + mf * 16 + l15;
        if (r > M - 1) r = M - 1;              // clamp tail rows (stores guarded)
        aoff[mf] = (size_t)r * K + kg * 8;
    }
    #pragma unroll
    for (int nf = 0; nf < NF; ++nf) {
        int c = colbase + nf * 16 + l15;
        boff[nf] = (size_t)c * K + kg * 8;
    }

    f32x4 acc[MF][NF];
    #pragma unroll
    for (int mf = 0; mf < MF; ++mf)
        #pragma unroll
        for (int nf = 0; nf < NF; ++nf)
            acc[mf][nf] = (f32x4){0.f, 0.f, 0.f, 0.f};

    #pragma unroll 2
    for (int k0 = 0; k0 < K; k0 += 32) {
        bf16x8 af[MF], bf[NF];
        #pragma unroll
        for (int mf = 0; mf < MF; ++mf)
            af[mf] = *(const bf16x8*)(A + aoff[mf] + k0);
        #pragma unroll
        for (int nf = 0; nf < NF; ++nf)
            bf[nf] = *(const bf16x8*)(Bt + boff[nf] + k0);
        #pragma unroll
        for (int mf = 0; mf < MF; ++mf)
            #pragma unroll
            for (int nf = 0; nf < NF; ++nf)
                acc[mf][nf] = __builtin_amdgcn_mfma_f32_16x16x32_bf16(af[mf], bf[nf], acc[mf][nf], 0, 0, 0);
    }

    #pragma unroll
    for (int mf = 0; mf < MF; ++mf)
        #pragma unroll
        for (int j = 0; j < 4; ++j) {
            int r = rowbase + mf * 16 + kg * 4 + j;
            if (r < M) {
                #pragma unroll
                for (int nf = 0; nf < NF; ++nf) {
                    int c = colbase + nf * 16 + l15;
                    if (STORE_BF16)
                        ((__bf16*)Cout)[(size_t)r * N + c] = (__bf16)acc[mf][nf][j];
                    else
                        ((float*)Cout)[(size_t)r * N + c] = acc[mf][nf][j];
                }
            }
        }
}

// ---------------------------------------------------------------------------
// Fused prep: W1/W2 transpose to bf16, attention vectors folded through W,
// graph-segment starts, cnt zeroing. Range-dispatched, no syncs needed.
//   [0, 131072)           cvtw W1
//   [131072, 196608)      cvtw W2
//   [196608, 199680)      attvec (3072)
//   [199680, 199680+N)    gstart
//   [199680+N, 199680+2N) cnt zero
// ---------------------------------------------------------------------------
__global__ void prep_kernel(const float* __restrict__ W1, const float* __restrict__ W2,
                            const float* __restrict__ as1w, const float* __restrict__ ad1w,
                            const float* __restrict__ as2w, const float* __restrict__ ad2w,
                            const int* __restrict__ batch,
                            __bf16* __restrict__ w1t, __bf16* __restrict__ w2t,
                            float* __restrict__ wsd1, float* __restrict__ wsd2,
                            int* __restrict__ gstart, int* __restrict__ cnt,
                            int N, int G)
{
    int t = blockIdx.x * 256 + threadIdx.x;
    if (t < 131072) {
        int i = t;
        int k = i >> 9, n = i & 511;
        w1t[n * 256 + k] = (__bf16)W1[i];
    } else if (t < 196608) {
        int j = t - 131072;
        int k = j >> 7, n = j & 127;
        w2t[n * 512 + k] = (__bf16)W2[j];
    } else if (t < 199680) {
        int t2 = t - 196608;
        if (t2 < 2048) {
            int k = t2 >> 3, v = t2 & 7, h = v >> 1;
            const float* av = (v & 1) ? (ad1w + h * 128) : (as1w + h * 128);
            float s = 0.f;
            for (int c = 0; c < 128; ++c) s += W1[k * 512 + h * 128 + c] * av[c];
            wsd1[v * 256 + k] = s;
        } else {
            int t3 = t2 - 2048;
            int k = t3 >> 1, v = t3 & 1;
            const float* av = v ? ad2w : as2w;
            float s = 0.f;
            for (int c = 0; c < 128; ++c) s += W2[k * 128 + c] * av[c];
            wsd2[v * 512 + k] = s;
        }
    } else if (t < 199680 + N) {
        int n = t - 199680;
        int b    = batch[n];
        int prev = (n == 0) ? -1 : batch[n - 1];
        for (int g = prev + 1; g <= b; ++g) gstart[g] = n;
        if (n == N - 1) {
            for (int g = b + 1; g <= G; ++g) gstart[g] = N;
        }
    } else if (t < 199680 + 2 * N) {
        cnt[t - 199680 - N] = 0;
    }
}

// ---------------------------------------------------------------------------
// x -> bf16 + fused layer-1 attention scores (as1/ad1 = x . wsd1[v]).
// ---------------------------------------------------------------------------
__global__ __launch_bounds__(256) void cvtx_kernel(
    const float* __restrict__ x, const float* __restrict__ wsd1,
    __bf16* __restrict__ xb, float* __restrict__ as1_, float* __restrict__ ad1_, int N)
{
    int wave = threadIdx.x >> 6, lane = threadIdx.x & 63;
    int n = blockIdx.x * 4 + wave;
    if (n >= N) return;
    float4 xv = *(const float4*)&x[(size_t)n * 256 + lane * 4];
    bf16x4 xo;
    xo[0] = (__bf16)xv.x; xo[1] = (__bf16)xv.y; xo[2] = (__bf16)xv.z; xo[3] = (__bf16)xv.w;
    *(bf16x4*)&xb[(size_t)n * 256 + lane * 4] = xo;
    float p[8];
    #pragma unroll
    for (int v = 0; v < 8; ++v) {
        float4 wv = *(const float4*)&wsd1[v * 256 + lane * 4];
        p[v] = xv.x * wv.x + xv.y * wv.y + xv.z * wv.z + xv.w * wv.w;
    }
    #pragma unroll
    for (int v = 0; v < 8; ++v)
        #pragma unroll
        for (int s = 1; s < 64; s <<= 1) p[v] += __shfl_xor(p[v], s);
    if (lane == 0) {
        #pragma unroll
        for (int h = 0; h < 4; ++h) {
            as1_[n * 4 + h] = p[2 * h];
            ad1_[n * 4 + h] = p[2 * h + 1];
        }
    }
}

// ---------------------------------------------------------------------------
// CSR build.
// ---------------------------------------------------------------------------
__global__ void count_kernel(const int* __restrict__ ei, int* __restrict__ cnt,
                             int ET, int E0)
{
    int e = blockIdx.x * blockDim.x + threadIdx.x;
    if (e >= ET) return;
    int d = (e < E0) ? ei[E0 + e] : (e - E0);
    atomicAdd(&cnt[d], 1);
}

// Single-block exclusive scan: 1024 threads x CHUNK elements each.
__global__ __launch_bounds__(1024) void scan_fused(
    const int* __restrict__ cnt, int* __restrict__ offs, int* __restrict__ cur, int n)
{
    constexpr int CHUNK = 20;   // 1024*20 = 20480 >= N
    int t = threadIdx.x;
    int base = t * CHUNK;
    int v[CHUNK];
    int s = 0;
    #pragma unroll
    for (int i = 0; i < CHUNK; ++i) {
        int idx = base + i;
        int xv = (idx < n) ? cnt[idx] : 0;
        v[i] = s; s += xv;
    }
    int lane = t & 63, w = t >> 6;
    int sc = s;
    #pragma unroll
    for (int d = 1; d < 64; d <<= 1) {
        int o = __shfl_up(sc, d);
        if (lane >= d) sc += o;
    }
    __shared__ int wt[16], wb[17];
    if (lane == 63) wt[w] = sc;
    __syncthreads();
    if (t == 0) {
        int acc = 0;
        for (int i = 0; i < 16; ++i) { wb[i] = acc; acc += wt[i]; }
        wb[16] = acc;
    }
    __syncthreads();
    int ebase = wb[w] + (sc - s);
    #pragma unroll
    for (int i = 0; i < CHUNK; ++i) {
        int idx = base + i;
        if (idx < n) {
            int o = ebase + v[i];
            offs[idx] = o;
            cur[idx]  = o;
        }
    }
    if (t == 0) offs[n] = wb[16];
}

__global__ void scatter_kernel(const int* __restrict__ ei, int* __restrict__ cur,
                               int* __restrict__ eid, int ET, int E0)
{
    int e = blockIdx.x * blockDim.x + threadIdx.x;
    if (e >= ET) return;
    int d   = (e < E0) ? ei[E0 + e] : (e - E0);
    int pos = atomicAdd(&cur[d], 1);
    eid[pos] = e;
}

// ---------------------------------------------------------------------------
// Layer-1 aggregate: wave per dst node (4 nodes / 256-thr block). Lane owns
// cols lane*8..+7 (head = lane>>4). Pass 1: max (16-lane strided). Pass 2:
// FUSED den+accum (8-wide unrolled, den normalized at the end). Then bias +
// relu + bf16 store + fused layer-2 attention scores.
// ---------------------------------------------------------------------------
__global__ __launch_bounds__(256) void aggregate1_kernel(
    const __bf16* __restrict__ h1b, const int* __restrict__ offs,
    const int* __restrict__ eid, const int* __restrict__ ei,
    const float* __restrict__ as1_, const float* __restrict__ ad1_,
    const float* __restrict__ b1, const float* __restrict__ wsd2,
    __bf16* __restrict__ out1b, float* __restrict__ as2_, float* __restrict__ ad2_,
    int E0, int N)
{
    int wave = threadIdx.x >> 6, lane = threadIdx.x & 63;
    int n = blockIdx.x * 4 + wave;
    if (n >= N) return;
    int hd  = lane >> 4;
    int l16 = lane & 15;
    int s0 = offs[n], s1 = offs[n + 1];
    float adn = ad1_[n * 4 + hd];

    // pass 1: max
    float m = -1e30f;
    for (int j = s0 + l16; j < s1; j += 16) {
        int e = eid[j];
        int s = (e < E0) ? ei[e] : (e - E0);
        float v = as1_[s * 4 + hd] + adn;
        v = (v < 0.f) ? NEG_SLOPE * v : v;
        m = fmaxf(m, v);
    }
    #pragma unroll
    for (int t = 1; t < 16; t <<= 1) m = fmaxf(m, __shfl_xor(m, t));

    // pass 2: fused den + accumulate (unnormalized), 8-wide unroll
    float den = 0.f;
    float a[8] = {0.f, 0.f, 0.f, 0.f, 0.f, 0.f, 0.f, 0.f};
    const __bf16* hbase = h1b + lane * 8;
    int j = s0;
    for (; j + 7 < s1; j += 8) {
        int e_[8], s_[8];
        float v_[8];
        bf16x8 h_[8];
        #pragma unroll
        for (int i = 0; i < 8; ++i) e_[i] = eid[j + i];
        #pragma unroll
        for (int i = 0; i < 8; ++i) s_[i] = (e_[i] < E0) ? ei[e_[i]] : (e_[i] - E0);
        #pragma unroll
        for (int i = 0; i < 8; ++i) v_[i] = as1_[s_[i] * 4 + hd] + adn;
        #pragma unroll
        for (int i = 0; i < 8; ++i) h_[i] = *(const bf16x8*)(hbase + (size_t)s_[i] * 512);
        #pragma unroll
        for (int i = 0; i < 8; ++i) {
            float v = (v_[i] < 0.f) ? NEG_SLOPE * v_[i] : v_[i];
            float w = __expf(v - m);
            den += w;
            #pragma unroll
            for (int k = 0; k < 8; ++k)
                a[k] = fmaf(w, (float)h_[i][k], a[k]);
        }
    }
    for (; j < s1; ++j) {
        int e = eid[j];
        int s = (e < E0) ? ei[e] : (e - E0);
        float v = as1_[s * 4 + hd] + adn;
        v = (v < 0.f) ? NEG_SLOPE * v : v;
        float w = __expf(v - m);
        den += w;
        bf16x8 hv = *(const bf16x8*)(hbase + (size_t)s * 512);
        #pragma unroll
        for (int k = 0; k < 8; ++k) a[k] = fmaf(w, (float)hv[k], a[k]);
    }
    float inv = 1.f / (den + 1e-16f);

    bf16x8 ov;
    float ps = 0.f, pd = 0.f;
    #pragma unroll
    for (int i = 0; i < 8; ++i) {
        float o = fmaxf(a[i] * inv + b1[lane * 8 + i], 0.f);
        ov[i] = (__bf16)o;
        ps = fmaf(o, wsd2[lane * 8 + i], ps);
        pd = fmaf(o, wsd2[512 + lane * 8 + i], pd);
    }
    *(bf16x8*)&out1b[(size_t)n * 512 + lane * 8] = ov;
    #pragma unroll
    for (int t = 1; t < 64; t <<= 1) {
        ps += __shfl_xor(ps, t);
        pd += __shfl_xor(pd, t);
    }
    if (lane == 0) {
        as2_[n] = ps;
        ad2_[n] = pd;
    }
}

// ---------------------------------------------------------------------------
// Layer-2 aggregate (H=1): wave per dst node, lane owns 2 cols (bf16 h2).
// Pass 1 max, pass 2 fused den+accum 8-wide.
// ---------------------------------------------------------------------------
__global__ __launch_bounds__(256) void aggregate2_kernel(
    const __bf16* __restrict__ h2b, const int* __restrict__ offs,
    const int* __restrict__ eid, const int* __restrict__ ei,
    const float* __restrict__ as2_, const float* __restrict__ ad2_,
    const float* __restrict__ b2, float* __restrict__ out2, int E0, int N)
{
    int wave = threadIdx.x >> 6, lane = threadIdx.x & 63;
    int n = blockIdx.x * 4 + wave;
    if (n >= N) return;
    int s0 = offs[n], s1 = offs[n + 1];
    float adn = ad2_[n];

    float m = -1e30f;
    for (int j = s0 + lane; j < s1; j += 64) {
        int e = eid[j];
        int s = (e < E0) ? ei[e] : (e - E0);
        float v = as2_[s] + adn;
        v = (v < 0.f) ? NEG_SLOPE * v : v;
        m = fmaxf(m, v);
    }
    #pragma unroll
    for (int t = 1; t < 64; t <<= 1) m = fmaxf(m, __shfl_xor(m, t));

    float den = 0.f;
    float a0 = 0.f, a1 = 0.f;
    const __bf16* hbase = h2b + lane * 2;
    int j = s0;
    for (; j + 7 < s1; j += 8) {
        int e_[8], s_[8];
        float v_[8];
        bf16x2 h_[8];
        #pragma unroll
        for (int i = 0; i < 8; ++i) e_[i] = eid[j + i];
        #pragma unroll
        for (int i = 0; i < 8; ++i) s_[i] = (e_[i] < E0) ? ei[e_[i]] : (e_[i] - E0);
        #pragma unroll
        for (int i = 0; i < 8; ++i) v_[i] = as2_[s_[i]] + adn;
        #pragma unroll
        for (int i = 0; i < 8; ++i) h_[i] = *(const bf16x2*)(hbase + (size_t)s_[i] * 128);
        #pragma unroll
        for (int i = 0; i < 8; ++i) {
            float v = (v_[i] < 0.f) ? NEG_SLOPE * v_[i] : v_[i];
            float w = __expf(v - m);
            den += w;
            a0 = fmaf(w, (float)h_[i][0], a0);
            a1 = fmaf(w, (float)h_[i][1], a1);
        }
    }
    for (; j < s1; ++j) {
        int e = eid[j];
        int s = (e < E0) ? ei[e] : (e - E0);
        float v = as2_[s] + adn;
        v = (v < 0.f) ? NEG_SLOPE * v : v;
        float w = __expf(v - m);
        den += w;
        bf16x2 hv = *(const bf16x2*)(hbase + (size_t)s * 128);
        a0 = fmaf(w, (float)hv[0], a0);
        a1 = fmaf(w, (float)hv[1], a1);
    }
    float inv = 1.f / (den + 1e-16f);
    float2 o;
    o.x = a0 * inv + b2[lane * 2 + 0];
    o.y = a1 * inv + b2[lane * 2 + 1];
    *(float2*)&out2[(size_t)n * 128 + lane * 2] = o;
}

// ---------------------------------------------------------------------------
// Mean pool stage 1, then fused stage2 + FC head.
// ---------------------------------------------------------------------------
#define POOL_S 16
__global__ void pool_stage1(const float* __restrict__ out2, const int* __restrict__ gstart,
                            float* __restrict__ partial, int C)
{
    int g = blockIdx.x, slice = blockIdx.y;
    int c = threadIdx.x;
    int s = gstart[g], e = gstart[g + 1];
    int len = e - s;
    int chunk = (len + POOL_S - 1) / POOL_S;
    int n0 = s + slice * chunk;
    int n1 = min(n0 + chunk, e);
    float acc = 0.f;
    for (int n = n0; n < n1; ++n) acc += out2[(size_t)n * C + c];
    partial[((size_t)g * POOL_S + slice) * C + c] = acc;
}

__global__ __launch_bounds__(128) void pool_head(
    const float* __restrict__ partial, const int* __restrict__ gstart,
    const float* __restrict__ fc1W, const float* __restrict__ fc1b,
    const float* __restrict__ fc2W, const float* __restrict__ fc2b,
    float* __restrict__ out)
{
    int g = blockIdx.x;
    int t = threadIdx.x;       // 0..127
    __shared__ float pl[128];
    float acc = 0.f;
    #pragma unroll
    for (int s = 0; s < POOL_S; ++s)
        acc += partial[((size_t)g * POOL_S + s) * 128 + t];
    float cntf = (float)(gstart[g + 1] - gstart[g]);
    pl[t] = acc / fmaxf(cntf, 1.0f);
    __syncthreads();
    if (t < 64) {
        float v = 0.f;
        for (int c = 0; c < 128; ++c)
            v += pl[c] * fc1W[c * 64 + t];
        v = fmaxf(v + fc1b[t], 0.f) * fc2W[t];
        #pragma unroll
        for (int s = 32; s > 0; s >>= 1) v += __shfl_down(v, s);
        if (t == 0) out[g] = v + fc2b[0];
    }
}

// ---------------------------------------------------------------------------
extern "C" void kernel_launch(void* const* d_in, const int* in_sizes, int n_in,
                              void* d_out, int out_size, void* d_ws, size_t ws_size,
                              hipStream_t stream)
{
    const float* x    = (const float*)d_in[0];
    const int*   ei   = (const int*)d_in[1];
    const int*   batch= (const int*)d_in[2];
    const float* W1   = (const float*)d_in[3];
    const float* as1w = (const float*)d_in[4];
    const float* ad1w = (const float*)d_in[5];
    const float* b1   = (const float*)d_in[6];
    const float* W2   = (const float*)d_in[7];
    const float* as2w = (const float*)d_in[8];
    const float* ad2w = (const float*)d_in[9];
    const float* b2   = (const float*)d_in[10];
    const float* fc1W = (const float*)d_in[11];
    const float* fc1b = (const float*)d_in[12];
    const float* fc2W = (const float*)d_in[13];
    const float* fc2b = (const float*)d_in[14];
    float* out = (float*)d_out;

    const int D = 256, C = 128, HC = 512, G = 64;
    const int N  = in_sizes[0] / D;        // 20000
    const int E0 = in_sizes[1] / 2;        // 160000
    const int ET = E0 + N;

    char* p = (char*)d_ws;
    auto alloc = [&](size_t bytes) -> char* {
        char* r = p;
        p += (bytes + 255) & ~(size_t)255;
        return r;
    };
    __bf16* xb    = (__bf16*)alloc((size_t)N * D * 2);
    __bf16* h1b   = (__bf16*)alloc((size_t)N * HC * 2);
    __bf16* out1b = (__bf16*)alloc((size_t)N * HC * 2);
    __bf16* h2b   = (__bf16*)alloc((size_t)N * C * 2);
    float*  out2  = (float*)alloc((size_t)N * C * 4);
    __bf16* w1t   = (__bf16*)alloc((size_t)256 * 512 * 2);
    __bf16* w2t   = (__bf16*)alloc((size_t)512 * 128 * 2);
    float* wsd1 = (float*)alloc(8 * 256 * 4);
    float* wsd2 = (float*)alloc(2 * 512 * 4);
    float* as1_ = (float*)alloc((size_t)N * 4 * 4);
    float* ad1_ = (float*)alloc((size_t)N * 4 * 4);
    float* as2_ = (float*)alloc((size_t)N * 4);
    float* ad2_ = (float*)alloc((size_t)N * 4);
    int*   cnt    = (int*)alloc((size_t)N * 4);
    int*   cur    = (int*)alloc((size_t)N * 4);
    int*   offs   = (int*)alloc((size_t)(N + 1) * 4);
    int*   eid    = (int*)alloc((size_t)ET * 4);
    int*   gstart = (int*)alloc((size_t)(G + 1) * 4);
    float* partial= (float*)alloc((size_t)G * POOL_S * C * 4);

    // ---- Fused prep (no memsets anywhere) ----
    {
        int total = 199680 + 2 * N;
        prep_kernel<<<(total + 255) / 256, 256, 0, stream>>>(
            W1, W2, as1w, ad1w, as2w, ad2w, batch,
            w1t, w2t, wsd1, wsd2, gstart, cnt, N, G);
    }

    // ---- CSR build ----
    count_kernel<<<(ET + 255) / 256, 256, 0, stream>>>(ei, cnt, ET, E0);
    scan_fused<<<1, 1024, 0, stream>>>(cnt, offs, cur, N);
    scatter_kernel<<<(ET + 255) / 256, 256, 0, stream>>>(ei, cur, eid, ET, E0);

    // ---- x conversion + layer-1 attention scores ----
    cvtx_kernel<<<N / 4, 256, 0, stream>>>(x, wsd1, xb, as1_, ad1_, N);

    // ---- Layer 1 ----
    gemm_mfma<4, 4, true><<<dim3(HC / 128, (N + 127) / 128), 256, 0, stream>>>(
        xb, w1t, h1b, N, HC, D);
    aggregate1_kernel<<<(N + 3) / 4, 256, 0, stream>>>(
        h1b, offs, eid, ei, as1_, ad1_, b1, wsd2, out1b, as2_, ad2_, E0, N);

    // ---- Layer 2 ----
    gemm_mfma<2, 2, true><<<dim3(C / 64, (N + 63) / 64), 256, 0, stream>>>(
        out1b, w2t, h2b, N, C, HC);
    aggregate2_kernel<<<(N + 3) / 4, 256, 0, stream>>>(
        h2b, offs, eid, ei, as2_, ad2_, b2, out2, E0, N);

    // ---- Pool + head ----
    pool_stage1<<<dim3(G, POOL_S), C, 0, stream>>>(out2, gstart, partial, C);
    pool_head<<<G, 128, 0, stream>>>(partial, gstart, fc1W, fc1b, fc2W, fc2b, out);
}